// Round 10
// baseline (921.602 us; speedup 1.0000x reference)
//
#include <hip/hip_runtime.h>
#include <hip/hip_cooperative_groups.h>
#include <cfloat>
#include <cmath>

#define N_Q 4096
#define N_S 1600
#define DIM 1024
#define N_C 64
#define KNN 12
#define MAX_ITER 50
#define EPS_CONV 1e-4f
#define NBLK 256         // tail_loop grid size (16 groups x 16 blocks)

typedef _Float16 h8 __attribute__((ext_vector_type(8)));
typedef float    f4 __attribute__((ext_vector_type(4)));

__device__ __forceinline__ float wave_max64(float v){
  #pragma unroll
  for (int o = 32; o; o >>= 1) v = fmaxf(v, __shfl_xor(v, o, 64));
  return v;
}
__device__ __forceinline__ float wave_sum64(float v){
  #pragma unroll
  for (int o = 32; o; o >>= 1) v += __shfl_xor(v, o, 64);
  return v;
}
__device__ __forceinline__ float wave_min64(float v){
  #pragma unroll
  for (int o = 32; o; o >>= 1) v = fminf(v, __shfl_xor(v, o, 64));
  return v;
}

// coherent (device-visible) element accesses for cross-block-communicated data
__device__ __forceinline__ float aload(const float* p){
  return __hip_atomic_load(p, __ATOMIC_RELAXED, __HIP_MEMORY_SCOPE_AGENT);
}
__device__ __forceinline__ void astore(float* p, float v){
  __hip_atomic_store(p, v, __ATOMIC_RELAXED, __HIP_MEMORY_SCOPE_AGENT);
}
__device__ __forceinline__ int aloadi(const int* p){
  return __hip_atomic_load(p, __ATOMIC_RELAXED, __HIP_MEMORY_SCOPE_AGENT);
}
__device__ __forceinline__ void astorei(int* p, int v){
  __hip_atomic_store(p, v, __ATOMIC_RELAXED, __HIP_MEMORY_SCOPE_AGENT);
}

// ---- prototypes: segment mean, stored TRANSPOSED Pt[f][c]; per-class sqnorm.
__global__ __launch_bounds__(256) void proto_kernel(
    const float* __restrict__ fs, const int* __restrict__ ys,
    float* __restrict__ Pt, float* __restrict__ pn)
{
  const int c = blockIdx.x, t = threadIdx.x;
  float a0 = 0.f, a1 = 0.f, a2 = 0.f, a3 = 0.f;
  int cnt = 0;
  for (int i = 0; i < N_S; i++){
    if (ys[i] == c){
      const float* r = fs + (size_t)i * DIM;
      a0 += r[t]; a1 += r[t + 256]; a2 += r[t + 512]; a3 += r[t + 768];
      cnt++;
    }
  }
  const float inv = 1.0f / fmaxf((float)cnt, 1.0f);
  const float v0 = a0*inv, v1 = a1*inv, v2 = a2*inv, v3 = a3*inv;
  Pt[(t      )*N_C + c] = v0;
  Pt[(t + 256)*N_C + c] = v1;
  Pt[(t + 512)*N_C + c] = v2;
  Pt[(t + 768)*N_C + c] = v3;
  __shared__ float red[256];
  red[t] = v0*v0 + v1*v1 + v2*v2 + v3*v3;
  __syncthreads();
  for (int o = 128; o; o >>= 1){ if (t < o) red[t] += red[t + o]; __syncthreads(); }
  if (t == 0) pn[c] = red[0];
}

// ---- fused per-row sqnorm + fp32 -> (f16 hi, f16 lo) split.
__global__ __launch_bounds__(256) void prep_kernel(
    const float* __restrict__ X, float* __restrict__ qn,
    _Float16* __restrict__ Xh, _Float16* __restrict__ Xl)
{
  const int i = blockIdx.x, t = threadIdx.x;
  const float* r = X + (size_t)i * DIM;
  const float v0 = r[t], v1 = r[t+256], v2 = r[t+512], v3 = r[t+768];
  const size_t b = (size_t)i * DIM;
  _Float16 h0 = (_Float16)v0, h1 = (_Float16)v1, h2 = (_Float16)v2, h3 = (_Float16)v3;
  Xh[b + t      ] = h0; Xl[b + t      ] = (_Float16)(v0 - (float)h0);
  Xh[b + t + 256] = h1; Xl[b + t + 256] = (_Float16)(v1 - (float)h1);
  Xh[b + t + 512] = h2; Xl[b + t + 512] = (_Float16)(v2 - (float)h2);
  Xh[b + t + 768] = h3; Xl[b + t + 768] = (_Float16)(v3 - (float)h3);
  __shared__ float red[256];
  red[t] = v0*v0 + v1*v1 + v2*v2 + v3*v3;
  __syncthreads();
  for (int o = 128; o; o >>= 1){ if (t < o) red[t] += red[t + o]; __syncthreads(); }
  if (t == 0) qn[i] = red[0];
}

// ---- pairwise distances via f16 split-precision MFMA (unchanged from R8/R9).
__global__ __launch_bounds__(256, 2) void dist_mfma(
    const _Float16* __restrict__ Xh, const _Float16* __restrict__ Xl,
    const float* __restrict__ qn, float* __restrict__ Dq)
{
  const int t = threadIdx.x, w = t >> 6, l = t & 63;
  const int i0 = blockIdx.y * 128 + (w >> 1) * 64;
  const int j0 = blockIdx.x * 128 + (w & 1) * 64;
  const int fr = l & 15;
  const int kq = (l >> 4) * 8;

  f4 acc[4][4];
  #pragma unroll
  for (int a = 0; a < 4; a++)
    #pragma unroll
    for (int b = 0; b < 4; b++) acc[a][b] = (f4){0.f, 0.f, 0.f, 0.f};

  const _Float16* pAh = Xh + (size_t)(i0 + fr) * DIM + kq;
  const _Float16* pAl = Xl + (size_t)(i0 + fr) * DIM + kq;
  const _Float16* pBh = Xh + (size_t)(j0 + fr) * DIM + kq;
  const _Float16* pBl = Xl + (size_t)(j0 + fr) * DIM + kq;

  #pragma unroll 1
  for (int k0 = 0; k0 < DIM; k0 += 32){
    h8 ah[4], al[4];
    #pragma unroll
    for (int sm = 0; sm < 4; sm++){
      const size_t o = (size_t)(sm * 16) * DIM + k0;
      ah[sm] = *(const h8*)(pAh + o);
      al[sm] = *(const h8*)(pAl + o);
    }
    #pragma unroll
    for (int sn = 0; sn < 4; sn++){
      const size_t o = (size_t)(sn * 16) * DIM + k0;
      h8 bh = *(const h8*)(pBh + o);
      h8 bl = *(const h8*)(pBl + o);
      #pragma unroll
      for (int sm = 0; sm < 4; sm++){
        acc[sm][sn] = __builtin_amdgcn_mfma_f32_16x16x32_f16(ah[sm], bh, acc[sm][sn], 0, 0, 0);
        acc[sm][sn] = __builtin_amdgcn_mfma_f32_16x16x32_f16(ah[sm], bl, acc[sm][sn], 0, 0, 0);
        acc[sm][sn] = __builtin_amdgcn_mfma_f32_16x16x32_f16(al[sm], bh, acc[sm][sn], 0, 0, 0);
      }
    }
  }

  const int cr = (l >> 4) * 4;
  const int cc = l & 15;
  #pragma unroll
  for (int sm = 0; sm < 4; sm++){
    #pragma unroll
    for (int r = 0; r < 4; r++){
      const int row = i0 + sm * 16 + cr + r;
      const float qi = qn[row];
      float* dstrow = &Dq[(size_t)row * N_Q];
      #pragma unroll
      for (int sn = 0; sn < 4; sn++){
        const int col = j0 + sn * 16 + cc;
        float d2 = qi + qn[col] - 2.0f * acc[sm][sn][r];
        dstrow[col] = sqrtf(fmaxf(d2, 0.f));
      }
    }
  }
}

// ---- per-row 13 smallest (ties -> smaller index), row in registers.
__global__ __launch_bounds__(256) void topk_kernel(
    const float* __restrict__ Dq, int* __restrict__ nbr,
    float* __restrict__ dnbr, float* __restrict__ sigma)
{
  const int i = blockIdx.x, t = threadIdx.x;
  const float* row = Dq + (size_t)i * N_Q;
  float r[16];
  #pragma unroll
  for (int u = 0; u < 16; u++) r[u] = row[t + u * 256];

  __shared__ float pvf[4];
  __shared__ int   pif[4];
  __shared__ int   bwi_s;

  for (int s = 0; s < KNN + 1; s++){
    float best = FLT_MAX; int bj = 0x7fffffff;
    #pragma unroll
    for (int u = 0; u < 16; u++){
      float v = r[u];
      if (v < best){ best = v; bj = t + u * 256; }
    }
    #pragma unroll
    for (int o = 32; o; o >>= 1){
      float ov = __shfl_xor(best, o, 64); int oj = __shfl_xor(bj, o, 64);
      if (ov < best || (ov == best && oj < bj)){ best = ov; bj = oj; }
    }
    if ((t & 63) == 0){ pvf[t >> 6] = best; pif[t >> 6] = bj; }
    __syncthreads();
    if (t == 0){
      float bv = pvf[0]; int bi2 = pif[0];
      #pragma unroll
      for (int w2 = 1; w2 < 4; w2++){
        float v2 = pvf[w2]; int i2 = pif[w2];
        if (v2 < bv || (v2 == bv && i2 < bi2)){ bv = v2; bi2 = i2; }
      }
      bwi_s = bi2;
      if (s >= 1){ nbr[i*KNN + s - 1] = bi2; dnbr[i*KNN + s - 1] = bv; }
      if (s == KNN) sigma[i] = bv + 1e-8f;
    }
    __syncthreads();
    const int widx = bwi_s;
    if ((widx & 255) == t) r[widx >> 8] = FLT_MAX;
  }
}

// ============ hierarchical monotonic grid barrier (setup phases only) ============
__device__ __forceinline__ void gbar_leader(int* garr, int* gcnt, int* gen, int target){
  const int g = blockIdx.x >> 4;
  int old = __hip_atomic_fetch_add(&garr[g * 32], 1, __ATOMIC_RELAXED, __HIP_MEMORY_SCOPE_AGENT);
  if ((old & 15) == 15){
    int o2 = __hip_atomic_fetch_add(gcnt, 1, __ATOMIC_RELAXED, __HIP_MEMORY_SCOPE_AGENT);
    if ((o2 & 15) == 15)
      __hip_atomic_fetch_add(gen, 1, __ATOMIC_RELAXED, __HIP_MEMORY_SCOPE_AGENT);
  }
  while (__hip_atomic_load(gen, __ATOMIC_RELAXED, __HIP_MEMORY_SCOPE_AGENT) < target)
    __builtin_amdgcn_s_sleep(1);
}

// ---- fused tail. R10 change: the while-loop has NO grid barrier. Rows
//      synchronize via per-row dataflow flags: after storing y_p (write-
//      through) the wave drains (s_waitcnt 0) and lane0 publishes
//      flag[row]=p+1; a reader at phase p polls flag[col]>=p for its ~24
//      neighbors (one lane per edge, __all ballot). W is SYMMETRIC, so the
//      ping-pong buffer is race-free: B may overwrite y_{p-1}[B] at phase
//      p+1 only after seeing flag[A]>=p+1, which A sets only after its
//      phase-p gathers read y_{p-1}[B]. Convergence: R9's 3-phase-slack
//      delayed check, guarded by cnt[j]==NBLK (leader publishes delta_j
//      relaxed at phase j+1, then cnt[j]++ RELEASE at phase j+2 -- the
//      release waitcnt covers the phase-old max, so no stall). All rows
//      read the same deterministic global delta -> all break at the same
//      iteration i; output argmax(y_i). Exact reference semantics.
__global__ __launch_bounds__(1024, 4) void tail_loop(
    const float* __restrict__ Xq, const float* __restrict__ Pt,
    const float* __restrict__ pn, const float* __restrict__ qn,
    const int* __restrict__ nbr, const float* __restrict__ dnbr,
    const float* __restrict__ sigma,
    float* d2min, float* denom, float* wh,
    float* rowsum, int* indeg, int* rowptr, int* fillc,
    int* colA, float* wA, float* buf0, float* buf1, float* deltas,
    int* cntArr, int* flag,
    int* gcnt, int* gen, int* garr, int* __restrict__ out)
{
  __shared__ int   sdm[2];
  __shared__ int   ipart[1024];
  __shared__ int   hist[1024];
  __shared__ float cand[4096];
  __shared__ int   candn, b1s, b2s;

  const int tid  = threadIdx.x;
  const int lane = tid & 63;
  const int wv   = tid >> 6;
  const int row  = blockIdx.x * 16 + wv;
  if (tid == 0){ sdm[0] = 0; sdm[1] = 0; }

  // ---------- P0a: a-row (kept in registers) ----------
  const float* xr = Xq + (size_t)row * DIM;
  float dp[8];
  #pragma unroll
  for (int u = 0; u < 8; u++) dp[u] = 0.f;
  for (int f = 0; f < DIM; f += 8){
    #pragma unroll
    for (int u = 0; u < 8; u++)
      dp[u] = fmaf(xr[f + u], Pt[(f + u) * N_C + lane], dp[u]);
  }
  const float dot = ((dp[0]+dp[1])+(dp[2]+dp[3])) + ((dp[4]+dp[5])+(dp[6]+dp[7]));
  const float av  = fmaxf(qn[row] + pn[lane] - 2.0f * dot, 0.0f);
  const float d2m = wave_min64(av);
  if (lane == 0) astore(&d2min[row], d2m);

  // ---------- P0b: edge weights + degrees ----------
  const int e = blockIdx.x * 1024 + tid;
  if (e < N_Q * KNN){
    const int i = e / KNN;
    const int j = nbr[e];
    float wgt = 0.5f * expf(-dnbr[e] / (sigma[i] * sigma[j]));
    astore(&wh[e], wgt);
    atomicAdd(&rowsum[i], wgt);
    atomicAdd(&rowsum[j], wgt);
    atomicAdd(&indeg[j], 1);
  }

  __syncthreads();
  if (tid == 0) gbar_leader(garr, gcnt, gen, 1);
  __syncthreads();

  // ---------- P1: y0 + scan (block 0) + median (block 1) ----------
  float xv = -av;
  float m = wave_max64(xv), ee = expf(xv - m), ss = wave_sum64(ee);
  float y0v = ee / ss;
  astore(&buf0[row * N_C + lane], y0v);

  if (blockIdx.x == 0){
    const int base = tid * 4;
    int c0 = aloadi(&indeg[base]),     c1 = aloadi(&indeg[base + 1]);
    int c2 = aloadi(&indeg[base + 2]), c3 = aloadi(&indeg[base + 3]);
    const int s4 = c0 + c1 + c2 + c3;
    ipart[tid] = s4;
    __syncthreads();
    for (int off = 1; off < 1024; off <<= 1){
      int v = (tid >= off) ? ipart[tid - off] : 0;
      __syncthreads();
      ipart[tid] += v;
      __syncthreads();
    }
    int run = ipart[tid] - s4;
    astorei(&rowptr[base    ], KNN * (base    ) + run); run += c0;
    astorei(&rowptr[base + 1], KNN * (base + 1) + run); run += c1;
    astorei(&rowptr[base + 2], KNN * (base + 2) + run); run += c2;
    astorei(&rowptr[base + 3], KNN * (base + 3) + run);
    if (tid == 1023) astorei(&rowptr[N_Q], KNN * N_Q + ipart[1023]);
  }
  if (blockIdx.x == 1){
    const int base = tid * 4;
    float dv[4];
    #pragma unroll
    for (int u = 0; u < 4; u++) dv[u] = sqrtf(aload(&d2min[base + u]));
    float mn = fminf(fminf(dv[0], dv[1]), fminf(dv[2], dv[3]));
    float mx = fmaxf(fmaxf(dv[0], dv[1]), fmaxf(dv[2], dv[3]));
    mn = wave_min64(mn); mx = wave_max64(mx);
    if (lane == 0){ cand[wv] = mn; cand[wv + 16] = mx; }
    __syncthreads();
    if (tid == 0){
      float a = cand[0], b = cand[16];
      for (int k = 1; k < 16; k++){ a = fminf(a, cand[k]); b = fmaxf(b, cand[16 + k]); }
      cand[32] = a; cand[33] = b;
    }
    __syncthreads();
    mn = cand[32]; mx = cand[33];
    const float rng = mx - mn;
    const float scale = (rng > 0.f) ? (1024.0f / rng) : 0.f;
    hist[tid] = 0;
    __syncthreads();
    int bidx[4];
    #pragma unroll
    for (int u = 0; u < 4; u++){
      int b = (int)((dv[u] - mn) * scale);
      b = b < 0 ? 0 : (b > 1023 ? 1023 : b);
      bidx[u] = b;
      atomicAdd(&hist[b], 1);
    }
    __syncthreads();
    for (int off = 1; off < 1024; off <<= 1){
      int v = (tid >= off) ? hist[tid - off] : 0;
      __syncthreads();
      hist[tid] += v;
      __syncthreads();
    }
    if (hist[tid] >= 2048 && (tid == 0 || hist[tid - 1] < 2048)) b1s = tid;
    if (hist[tid] >= 2049 && (tid == 0 || hist[tid - 1] < 2049)) b2s = tid;
    if (tid == 0) candn = 0;
    __syncthreads();
    const int b1 = b1s, b2 = b2s;
    const int cntBefore = (b1 > 0) ? hist[b1 - 1] : 0;
    #pragma unroll
    for (int u = 0; u < 4; u++){
      if (bidx[u] >= b1 && bidx[u] <= b2){
        int pos = atomicAdd(&candn, 1);
        cand[pos] = dv[u];
      }
    }
    __syncthreads();
    const int mcnt = candn;
    int P = 2; while (P < mcnt) P <<= 1;
    for (int i2 = mcnt + tid; i2 < P; i2 += 1024) cand[i2] = FLT_MAX;
    __syncthreads();
    for (int k = 2; k <= P; k <<= 1){
      for (int st = k >> 1; st > 0; st >>= 1){
        for (int i2 = tid; i2 < P; i2 += 1024){
          int j2 = i2 ^ st;
          if (j2 > i2){
            float a2 = cand[i2], b3 = cand[j2];
            bool up = ((i2 & k) == 0);
            if (up ? (a2 > b3) : (a2 < b3)){ cand[i2] = b3; cand[j2] = a2; }
          }
        }
        __syncthreads();
      }
    }
    if (tid == 0){
      float v1 = cand[2047 - cntBefore], v2 = cand[2048 - cntBefore];
      float med = 0.5f * (v1 + v2);
      astore(denom, 2.0f * med * med + 1e-8f);
    }
  }

  __syncthreads();
  if (tid == 0) gbar_leader(garr, gcnt, gen, 2);
  __syncthreads();

  // ---------- P2: CSR fill + per-row coef ----------
  if (e < N_Q * KNN){
    const int i = e / KNN, tt = e % KNN;
    const int j = nbr[e];
    const float wgt = aload(&wh[e]);
    const int p = aloadi(&rowptr[i]) + tt;
    colA[p] = j * N_C; wA[p] = wgt;
    const int q = aloadi(&rowptr[j]) + KNN + atomicAdd(&fillc[j], 1);
    colA[q] = i * N_C; wA[q] = wgt;
  }
  const float cf = expf(-d2m / aload(denom)) / (aload(&rowsum[row]) + 1e-8f);
  const int p0  = aloadi(&rowptr[row]);
  const int p1v = aloadi(&rowptr[row + 1]);

  // one-time flush+invalidate so colA/wA are plain-cacheable hereafter;
  // barrier 3 also guarantees every row's y0 is globally visible.
  __builtin_amdgcn_fence(__ATOMIC_RELEASE, "agent");
  __syncthreads();
  if (tid == 0) gbar_leader(garr, gcnt, gen, 3);
  __syncthreads();
  __builtin_amdgcn_fence(__ATOMIC_ACQUIRE, "agent");

  // ---------- P3: barrier-free dataflow while-loop, phases p = 1..53 ----------
  // y_q lives in buf[q&1]; flag[row]=q+1 once y_q is globally visible.
  float p1r = y0v, p2r = 0.f, p3r = 0.f;
  for (int p = 1; p <= MAX_ITER + 3; p++){
    const float* src = ((p - 1) & 1) ? buf1 : buf0;
    float*       dst = (p & 1) ? buf1 : buf0;

    // convergence data (3-phase slack), completion-guarded
    float delta = 1e30f;
    if (p >= 3){
      while (aloadi(&cntArr[p - 3]) < NBLK) __builtin_amdgcn_s_sleep(1);
      delta = __int_as_float(aloadi((const int*)&deltas[p - 3]));
    }

    // wait for neighbors' y_{p-1} (skip p==1: barrier 3 covered y0)
    if (p > 1){
      while (1){
        int mn = 0x7fffffff;
        for (int b = p0 + lane; b < p1v; b += 64){
          int f = aloadi(&flag[colA[b] >> 6]);
          mn = f < mn ? f : mn;
        }
        if (__all(mn >= p)) break;
        __builtin_amdgcn_s_sleep(1);
      }
    }

    // gather + softmax
    float s0=0.f,s1=0.f,s2=0.f,s3=0.f,s4=0.f,s5=0.f,s6=0.f,s7=0.f;
    int q = p0;
    for (; q + 8 <= p1v; q += 8){
      s0 = fmaf(wA[q    ], aload(&src[colA[q    ] + lane]), s0);
      s1 = fmaf(wA[q + 1], aload(&src[colA[q + 1] + lane]), s1);
      s2 = fmaf(wA[q + 2], aload(&src[colA[q + 2] + lane]), s2);
      s3 = fmaf(wA[q + 3], aload(&src[colA[q + 3] + lane]), s3);
      s4 = fmaf(wA[q + 4], aload(&src[colA[q + 4] + lane]), s4);
      s5 = fmaf(wA[q + 5], aload(&src[colA[q + 5] + lane]), s5);
      s6 = fmaf(wA[q + 6], aload(&src[colA[q + 6] + lane]), s6);
      s7 = fmaf(wA[q + 7], aload(&src[colA[q + 7] + lane]), s7);
    }
    for (; q < p1v; q++) s0 = fmaf(wA[q], aload(&src[colA[q] + lane]), s0);
    float xv2 = -av + cf * (((s0+s1)+(s2+s3)) + ((s4+s5)+(s6+s7)));
    float mm = wave_max64(xv2), e2 = expf(xv2 - mm), ss2 = wave_sum64(e2);
    float cur = e2 / ss2;

    // exit test for i = p-3 (all rows see identical delta -> uniform break)
    if (p >= 3 && (p - 3 == MAX_ITER || delta < EPS_CONV)) break;

    // publish y_p then flag (ordered by wave-level store drain)
    astore(&dst[row * N_C + lane], cur);
    float dm = wave_max64(fabsf(cur - p1r));
    if (lane == 0) atomicMax(&sdm[p & 1], __float_as_int(dm));
    __builtin_amdgcn_s_waitcnt(0);
    if (lane == 0) astorei(&flag[row], p + 1);
    __syncthreads();
    if (tid == 0){
      int sd = sdm[p & 1]; sdm[p & 1] = 0;
      if (p >= 2)
        __hip_atomic_fetch_add(&cntArr[p - 2], 1, __ATOMIC_RELEASE, __HIP_MEMORY_SCOPE_AGENT);
      __hip_atomic_fetch_max((int*)&deltas[p - 1], sd, __ATOMIC_RELAXED, __HIP_MEMORY_SCOPE_AGENT);
    }
    p3r = p2r; p2r = p1r; p1r = cur;
  }

  // argmax of y_i (p3r); first occurrence on ties
  float bv = p3r; int bi = lane;
  #pragma unroll
  for (int o = 32; o; o >>= 1){
    float ov = __shfl_xor(bv, o, 64); int oi = __shfl_xor(bi, o, 64);
    if (ov > bv || (ov == bv && oi < bi)){ bv = ov; bi = oi; }
  }
  if (lane == 0) out[row] = bi;
}

extern "C" void kernel_launch(void* const* d_in, const int* in_sizes, int n_in,
                              void* d_out, int out_size, void* d_ws, size_t ws_size,
                              hipStream_t stream)
{
  const float* feat_s = (const float*)d_in[0];
  const int*   y_s    = (const int*)d_in[1];
  const float* feat_q = (const float*)d_in[2];
  int* out = (int*)d_out;

  char* wp = (char*)d_ws;
  auto alloc = [&](size_t bytes) -> char* {
    char* p = wp;
    wp += (bytes + 255) & ~(size_t)255;
    return p;
  };
  float*     Dq  = (float*)alloc((size_t)N_Q * N_Q * 4);     // 64 MB
  _Float16*  Xh  = (_Float16*)alloc((size_t)N_Q * DIM * 2);  // 8 MB
  _Float16*  Xl  = (_Float16*)alloc((size_t)N_Q * DIM * 2);  // 8 MB
  float* Pt     = (float*)alloc((size_t)DIM * N_C * 4);
  float* pn     = (float*)alloc(N_C * 4);
  float* qn     = (float*)alloc(N_Q * 4);
  float* d2min  = (float*)alloc(N_Q * 4);
  float* denom  = (float*)alloc(256);
  int*   nbr    = (int*)alloc((size_t)N_Q * KNN * 4);
  float* dnbr   = (float*)alloc((size_t)N_Q * KNN * 4);
  float* sigma  = (float*)alloc(N_Q * 4);
  float* wh     = (float*)alloc((size_t)N_Q * KNN * 4);
  int*   rowptr = (int*)alloc((N_Q + 1) * 4);
  int*   colA   = (int*)alloc((size_t)2 * N_Q * KNN * 4);
  float* wA     = (float*)alloc((size_t)2 * N_Q * KNN * 4);
  float* buf0   = (float*)alloc((size_t)N_Q * N_C * 4);
  float* buf1   = (float*)alloc((size_t)N_Q * N_C * 4);
  // zero-region: rowsum | indeg | fillc | deltas | cnt | syncw | garr | flag
  char*  zbase  = alloc(N_Q*4 + N_Q*4 + N_Q*4 + 64*4 + 64*4 + 64*4 + 512*4 + N_Q*4);
  float* rowsum = (float*)(zbase);
  int*   indeg  = (int*)(zbase + N_Q*4);
  int*   fillc  = (int*)(zbase + N_Q*8);
  float* deltas = (float*)(zbase + N_Q*12);
  int*   cntA   = (int*)(zbase + N_Q*12 + 256);
  int*   syncw  = (int*)(zbase + N_Q*12 + 512);
  int*   garr   = (int*)(zbase + N_Q*12 + 768);
  int*   flag   = (int*)(zbase + N_Q*12 + 768 + 2048);
  const size_t zbytes = N_Q*12 + 768 + 2048 + N_Q*4;

  hipMemsetAsync(zbase, 0, zbytes, stream);

  proto_kernel <<<N_C, 256, 0, stream>>>(feat_s, y_s, Pt, pn);
  prep_kernel  <<<N_Q, 256, 0, stream>>>(feat_q, qn, Xh, Xl);
  dist_mfma    <<<dim3(N_Q/128, N_Q/128), 256, 0, stream>>>(Xh, Xl, qn, Dq);
  topk_kernel  <<<N_Q, 256, 0, stream>>>(Dq, nbr, dnbr, sigma);

  int* gcnt = &syncw[0];
  int* gen  = &syncw[32];
  const float* Xq = feat_q;
  void* args[] = {&Xq, &Pt, &pn, &qn, &nbr, &dnbr, &sigma,
                  &d2min, &denom, &wh, &rowsum, &indeg, &rowptr, &fillc,
                  &colA, &wA, &buf0, &buf1, &deltas, &cntA, &flag,
                  &gcnt, &gen, &garr, &out};
  hipLaunchCooperativeKernel((void*)tail_loop, dim3(NBLK), dim3(1024), args, 0, stream);
}

// Round 11
// 763.314 us; speedup vs baseline: 1.2074x; 1.2074x over previous
//
#include <hip/hip_runtime.h>
#include <hip/hip_cooperative_groups.h>
#include <cfloat>
#include <cmath>

#define N_Q 4096
#define N_S 1600
#define DIM 1024
#define N_C 64
#define KNN 12
#define MAX_ITER 50
#define EPS_CONV 1e-4f
#define NBLK 256         // tail_loop grid size

typedef _Float16 h8 __attribute__((ext_vector_type(8)));
typedef float    f4 __attribute__((ext_vector_type(4)));

__device__ __forceinline__ float wave_max64(float v){
  #pragma unroll
  for (int o = 32; o; o >>= 1) v = fmaxf(v, __shfl_xor(v, o, 64));
  return v;
}
__device__ __forceinline__ float wave_sum64(float v){
  #pragma unroll
  for (int o = 32; o; o >>= 1) v += __shfl_xor(v, o, 64);
  return v;
}
__device__ __forceinline__ float wave_min64(float v){
  #pragma unroll
  for (int o = 32; o; o >>= 1) v = fminf(v, __shfl_xor(v, o, 64));
  return v;
}

// coherent (device-visible) element accesses for cross-block-communicated data
__device__ __forceinline__ float aload(const float* p){
  return __hip_atomic_load(p, __ATOMIC_RELAXED, __HIP_MEMORY_SCOPE_AGENT);
}
__device__ __forceinline__ void astore(float* p, float v){
  __hip_atomic_store(p, v, __ATOMIC_RELAXED, __HIP_MEMORY_SCOPE_AGENT);
}
__device__ __forceinline__ int aloadi(const int* p){
  return __hip_atomic_load(p, __ATOMIC_RELAXED, __HIP_MEMORY_SCOPE_AGENT);
}
__device__ __forceinline__ void astorei(int* p, int v){
  __hip_atomic_store(p, v, __ATOMIC_RELAXED, __HIP_MEMORY_SCOPE_AGENT);
}

// ---- prototypes: segment mean, stored TRANSPOSED Pt[f][c]; per-class sqnorm.
__global__ __launch_bounds__(256) void proto_kernel(
    const float* __restrict__ fs, const int* __restrict__ ys,
    float* __restrict__ Pt, float* __restrict__ pn)
{
  const int c = blockIdx.x, t = threadIdx.x;
  float a0 = 0.f, a1 = 0.f, a2 = 0.f, a3 = 0.f;
  int cnt = 0;
  for (int i = 0; i < N_S; i++){
    if (ys[i] == c){
      const float* r = fs + (size_t)i * DIM;
      a0 += r[t]; a1 += r[t + 256]; a2 += r[t + 512]; a3 += r[t + 768];
      cnt++;
    }
  }
  const float inv = 1.0f / fmaxf((float)cnt, 1.0f);
  const float v0 = a0*inv, v1 = a1*inv, v2 = a2*inv, v3 = a3*inv;
  Pt[(t      )*N_C + c] = v0;
  Pt[(t + 256)*N_C + c] = v1;
  Pt[(t + 512)*N_C + c] = v2;
  Pt[(t + 768)*N_C + c] = v3;
  __shared__ float red[256];
  red[t] = v0*v0 + v1*v1 + v2*v2 + v3*v3;
  __syncthreads();
  for (int o = 128; o; o >>= 1){ if (t < o) red[t] += red[t + o]; __syncthreads(); }
  if (t == 0) pn[c] = red[0];
}

// ---- fused per-row sqnorm + fp32 -> (f16 hi, f16 lo) split.
__global__ __launch_bounds__(256) void prep_kernel(
    const float* __restrict__ X, float* __restrict__ qn,
    _Float16* __restrict__ Xh, _Float16* __restrict__ Xl)
{
  const int i = blockIdx.x, t = threadIdx.x;
  const float* r = X + (size_t)i * DIM;
  const float v0 = r[t], v1 = r[t+256], v2 = r[t+512], v3 = r[t+768];
  const size_t b = (size_t)i * DIM;
  _Float16 h0 = (_Float16)v0, h1 = (_Float16)v1, h2 = (_Float16)v2, h3 = (_Float16)v3;
  Xh[b + t      ] = h0; Xl[b + t      ] = (_Float16)(v0 - (float)h0);
  Xh[b + t + 256] = h1; Xl[b + t + 256] = (_Float16)(v1 - (float)h1);
  Xh[b + t + 512] = h2; Xl[b + t + 512] = (_Float16)(v2 - (float)h2);
  Xh[b + t + 768] = h3; Xl[b + t + 768] = (_Float16)(v3 - (float)h3);
  __shared__ float red[256];
  red[t] = v0*v0 + v1*v1 + v2*v2 + v3*v3;
  __syncthreads();
  for (int o = 128; o; o >>= 1){ if (t < o) red[t] += red[t + o]; __syncthreads(); }
  if (t == 0) qn[i] = red[0];
}

// ---- pairwise distances via f16 split-precision MFMA (unchanged from R8-R10).
__global__ __launch_bounds__(256, 2) void dist_mfma(
    const _Float16* __restrict__ Xh, const _Float16* __restrict__ Xl,
    const float* __restrict__ qn, float* __restrict__ Dq)
{
  const int t = threadIdx.x, w = t >> 6, l = t & 63;
  const int i0 = blockIdx.y * 128 + (w >> 1) * 64;
  const int j0 = blockIdx.x * 128 + (w & 1) * 64;
  const int fr = l & 15;
  const int kq = (l >> 4) * 8;

  f4 acc[4][4];
  #pragma unroll
  for (int a = 0; a < 4; a++)
    #pragma unroll
    for (int b = 0; b < 4; b++) acc[a][b] = (f4){0.f, 0.f, 0.f, 0.f};

  const _Float16* pAh = Xh + (size_t)(i0 + fr) * DIM + kq;
  const _Float16* pAl = Xl + (size_t)(i0 + fr) * DIM + kq;
  const _Float16* pBh = Xh + (size_t)(j0 + fr) * DIM + kq;
  const _Float16* pBl = Xl + (size_t)(j0 + fr) * DIM + kq;

  #pragma unroll 1
  for (int k0 = 0; k0 < DIM; k0 += 32){
    h8 ah[4], al[4];
    #pragma unroll
    for (int sm = 0; sm < 4; sm++){
      const size_t o = (size_t)(sm * 16) * DIM + k0;
      ah[sm] = *(const h8*)(pAh + o);
      al[sm] = *(const h8*)(pAl + o);
    }
    #pragma unroll
    for (int sn = 0; sn < 4; sn++){
      const size_t o = (size_t)(sn * 16) * DIM + k0;
      h8 bh = *(const h8*)(pBh + o);
      h8 bl = *(const h8*)(pBl + o);
      #pragma unroll
      for (int sm = 0; sm < 4; sm++){
        acc[sm][sn] = __builtin_amdgcn_mfma_f32_16x16x32_f16(ah[sm], bh, acc[sm][sn], 0, 0, 0);
        acc[sm][sn] = __builtin_amdgcn_mfma_f32_16x16x32_f16(ah[sm], bl, acc[sm][sn], 0, 0, 0);
        acc[sm][sn] = __builtin_amdgcn_mfma_f32_16x16x32_f16(al[sm], bh, acc[sm][sn], 0, 0, 0);
      }
    }
  }

  const int cr = (l >> 4) * 4;
  const int cc = l & 15;
  #pragma unroll
  for (int sm = 0; sm < 4; sm++){
    #pragma unroll
    for (int r = 0; r < 4; r++){
      const int row = i0 + sm * 16 + cr + r;
      const float qi = qn[row];
      float* dstrow = &Dq[(size_t)row * N_Q];
      #pragma unroll
      for (int sn = 0; sn < 4; sn++){
        const int col = j0 + sn * 16 + cc;
        float d2 = qi + qn[col] - 2.0f * acc[sm][sn][r];
        dstrow[col] = sqrtf(fmaxf(d2, 0.f));
      }
    }
  }
}

// ---- per-row 13 smallest (ties -> smaller index), row in registers.
__global__ __launch_bounds__(256) void topk_kernel(
    const float* __restrict__ Dq, int* __restrict__ nbr,
    float* __restrict__ dnbr, float* __restrict__ sigma)
{
  const int i = blockIdx.x, t = threadIdx.x;
  const float* row = Dq + (size_t)i * N_Q;
  float r[16];
  #pragma unroll
  for (int u = 0; u < 16; u++) r[u] = row[t + u * 256];

  __shared__ float pvf[4];
  __shared__ int   pif[4];
  __shared__ int   bwi_s;

  for (int s = 0; s < KNN + 1; s++){
    float best = FLT_MAX; int bj = 0x7fffffff;
    #pragma unroll
    for (int u = 0; u < 16; u++){
      float v = r[u];
      if (v < best){ best = v; bj = t + u * 256; }
    }
    #pragma unroll
    for (int o = 32; o; o >>= 1){
      float ov = __shfl_xor(best, o, 64); int oj = __shfl_xor(bj, o, 64);
      if (ov < best || (ov == best && oj < bj)){ best = ov; bj = oj; }
    }
    if ((t & 63) == 0){ pvf[t >> 6] = best; pif[t >> 6] = bj; }
    __syncthreads();
    if (t == 0){
      float bv = pvf[0]; int bi2 = pif[0];
      #pragma unroll
      for (int w2 = 1; w2 < 4; w2++){
        float v2 = pvf[w2]; int i2 = pif[w2];
        if (v2 < bv || (v2 == bv && i2 < bi2)){ bv = v2; bi2 = i2; }
      }
      bwi_s = bi2;
      if (s >= 1){ nbr[i*KNN + s - 1] = bi2; dnbr[i*KNN + s - 1] = bv; }
      if (s == KNN) sigma[i] = bv + 1e-8f;
    }
    __syncthreads();
    const int widx = bwi_s;
    if ((widx & 255) == t) r[widx >> 8] = FLT_MAX;
  }
}

// ============ hierarchical monotonic grid barrier (setup phases only) ============
__device__ __forceinline__ void gbar_leader(int* garr, int* gcnt, int* gen, int target){
  const int g = blockIdx.x >> 4;
  int old = __hip_atomic_fetch_add(&garr[g * 32], 1, __ATOMIC_RELAXED, __HIP_MEMORY_SCOPE_AGENT);
  if ((old & 15) == 15){
    int o2 = __hip_atomic_fetch_add(gcnt, 1, __ATOMIC_RELAXED, __HIP_MEMORY_SCOPE_AGENT);
    if ((o2 & 15) == 15)
      __hip_atomic_fetch_add(gen, 1, __ATOMIC_RELAXED, __HIP_MEMORY_SCOPE_AGENT);
  }
  while (__hip_atomic_load(gen, __ATOMIC_RELAXED, __HIP_MEMORY_SCOPE_AGENT) < target)
    __builtin_amdgcn_s_sleep(1);
}

// ============ parallel-read flag barrier (loop phases; wave 0 only) ============
// No RMW anywhere: each block WRITES phase to its own 128B line; wave 0 polls
// all 256 flags in parallel (64 lanes x 4 loads = one latency round, vs the
// ~32-deep serialized RMW chain of the hierarchical barrier = ~5us of R8's
// 6.6us phase). Per-block deltas ride the same lines (delta store -> waitcnt
// -> flag store; parity slots so phase-p values survive until p+2, provably
// past all phase-p reads). Every block max-reduces the same 256 deltas ->
// identical deterministic global delta, exact R8 loop semantics.
__device__ __forceinline__ void pbar_wave0(
    int* bflag, int* bdelta, int ph, int* sdm, float* sdelta_sh, int lane)
{
  if (lane == 0){
    int myd = sdm[ph & 1]; sdm[ph & 1] = 0;
    astorei(&bdelta[(blockIdx.x * 2 + (ph & 1)) * 32], myd);
    __builtin_amdgcn_s_waitcnt(0);            // delta (and all prior y stores) drained
    astorei(&bflag[blockIdx.x * 32], ph);
  }
  while (1){
    int mn = 0x7fffffff;
    #pragma unroll
    for (int u = 0; u < 4; u++){
      int f = aloadi(&bflag[(lane + u * 64) * 32]);
      mn = f < mn ? f : mn;
    }
    if (__all(mn >= ph)) break;
    __builtin_amdgcn_s_sleep(1);
  }
  int mx = 0;                                 // deltas nonneg -> int compare ok
  #pragma unroll
  for (int u = 0; u < 4; u++){
    int d = aloadi(&bdelta[((lane + u * 64) * 2 + (ph & 1)) * 32]);
    mx = d > mx ? d : mx;
  }
  #pragma unroll
  for (int o = 32; o; o >>= 1){ int ox = __shfl_xor(mx, o, 64); mx = ox > mx ? ox : mx; }
  if (lane == 0) *sdelta_sh = __int_as_float(mx);
}

// ---- fused tail: setup phases unchanged (R7-proven); while-loop is R8's
//      synchronous shape with the parallel-read flag barrier.
__global__ __launch_bounds__(1024, 4) void tail_loop(
    const float* __restrict__ Xq, const float* __restrict__ Pt,
    const float* __restrict__ pn, const float* __restrict__ qn,
    const int* __restrict__ nbr, const float* __restrict__ dnbr,
    const float* __restrict__ sigma,
    float* d2min, float* denom, float* wh,
    float* rowsum, int* indeg, int* rowptr, int* fillc,
    int* colA, float* wA, float* buf0, float* buf1,
    int* bflag, int* bdelta,
    int* gcnt, int* gen, int* garr, int* __restrict__ out)
{
  __shared__ int   sdm[2];
  __shared__ float sdelta;
  __shared__ int   ipart[1024];
  __shared__ int   hist[1024];
  __shared__ float cand[4096];
  __shared__ int   candn, b1s, b2s;

  const int tid  = threadIdx.x;
  const int lane = tid & 63;
  const int wv   = tid >> 6;
  const int row  = blockIdx.x * 16 + wv;
  if (tid == 0){ sdm[0] = 0; sdm[1] = 0; }

  // ---------- P0a: a-row (kept in registers) ----------
  const float* xr = Xq + (size_t)row * DIM;
  float dp[8];
  #pragma unroll
  for (int u = 0; u < 8; u++) dp[u] = 0.f;
  for (int f = 0; f < DIM; f += 8){
    #pragma unroll
    for (int u = 0; u < 8; u++)
      dp[u] = fmaf(xr[f + u], Pt[(f + u) * N_C + lane], dp[u]);
  }
  const float dot = ((dp[0]+dp[1])+(dp[2]+dp[3])) + ((dp[4]+dp[5])+(dp[6]+dp[7]));
  const float av  = fmaxf(qn[row] + pn[lane] - 2.0f * dot, 0.0f);
  const float d2m = wave_min64(av);
  if (lane == 0) astore(&d2min[row], d2m);

  // ---------- P0b: edge weights + degrees ----------
  const int e = blockIdx.x * 1024 + tid;
  if (e < N_Q * KNN){
    const int i = e / KNN;
    const int j = nbr[e];
    float wgt = 0.5f * expf(-dnbr[e] / (sigma[i] * sigma[j]));
    astore(&wh[e], wgt);
    atomicAdd(&rowsum[i], wgt);
    atomicAdd(&rowsum[j], wgt);
    atomicAdd(&indeg[j], 1);
  }

  __syncthreads();
  if (tid == 0) gbar_leader(garr, gcnt, gen, 1);
  __syncthreads();

  // ---------- P1: y0 + scan (block 0) + median (block 1) ----------
  float xv = -av;
  float m = wave_max64(xv), ee = expf(xv - m), ss = wave_sum64(ee);
  float prev = ee / ss;                    // y0
  astore(&buf0[row * N_C + lane], prev);

  if (blockIdx.x == 0){
    const int base = tid * 4;
    int c0 = aloadi(&indeg[base]),     c1 = aloadi(&indeg[base + 1]);
    int c2 = aloadi(&indeg[base + 2]), c3 = aloadi(&indeg[base + 3]);
    const int s4 = c0 + c1 + c2 + c3;
    ipart[tid] = s4;
    __syncthreads();
    for (int off = 1; off < 1024; off <<= 1){
      int v = (tid >= off) ? ipart[tid - off] : 0;
      __syncthreads();
      ipart[tid] += v;
      __syncthreads();
    }
    int run = ipart[tid] - s4;
    astorei(&rowptr[base    ], KNN * (base    ) + run); run += c0;
    astorei(&rowptr[base + 1], KNN * (base + 1) + run); run += c1;
    astorei(&rowptr[base + 2], KNN * (base + 2) + run); run += c2;
    astorei(&rowptr[base + 3], KNN * (base + 3) + run);
    if (tid == 1023) astorei(&rowptr[N_Q], KNN * N_Q + ipart[1023]);
  }
  if (blockIdx.x == 1){
    const int base = tid * 4;
    float dv[4];
    #pragma unroll
    for (int u = 0; u < 4; u++) dv[u] = sqrtf(aload(&d2min[base + u]));
    float mn = fminf(fminf(dv[0], dv[1]), fminf(dv[2], dv[3]));
    float mx = fmaxf(fmaxf(dv[0], dv[1]), fmaxf(dv[2], dv[3]));
    mn = wave_min64(mn); mx = wave_max64(mx);
    if (lane == 0){ cand[wv] = mn; cand[wv + 16] = mx; }
    __syncthreads();
    if (tid == 0){
      float a = cand[0], b = cand[16];
      for (int k = 1; k < 16; k++){ a = fminf(a, cand[k]); b = fmaxf(b, cand[16 + k]); }
      cand[32] = a; cand[33] = b;
    }
    __syncthreads();
    mn = cand[32]; mx = cand[33];
    const float rng = mx - mn;
    const float scale = (rng > 0.f) ? (1024.0f / rng) : 0.f;
    hist[tid] = 0;
    __syncthreads();
    int bidx[4];
    #pragma unroll
    for (int u = 0; u < 4; u++){
      int b = (int)((dv[u] - mn) * scale);
      b = b < 0 ? 0 : (b > 1023 ? 1023 : b);
      bidx[u] = b;
      atomicAdd(&hist[b], 1);
    }
    __syncthreads();
    for (int off = 1; off < 1024; off <<= 1){
      int v = (tid >= off) ? hist[tid - off] : 0;
      __syncthreads();
      hist[tid] += v;
      __syncthreads();
    }
    if (hist[tid] >= 2048 && (tid == 0 || hist[tid - 1] < 2048)) b1s = tid;
    if (hist[tid] >= 2049 && (tid == 0 || hist[tid - 1] < 2049)) b2s = tid;
    if (tid == 0) candn = 0;
    __syncthreads();
    const int b1 = b1s, b2 = b2s;
    const int cntBefore = (b1 > 0) ? hist[b1 - 1] : 0;
    #pragma unroll
    for (int u = 0; u < 4; u++){
      if (bidx[u] >= b1 && bidx[u] <= b2){
        int pos = atomicAdd(&candn, 1);
        cand[pos] = dv[u];
      }
    }
    __syncthreads();
    const int mcnt = candn;
    int P = 2; while (P < mcnt) P <<= 1;
    for (int i2 = mcnt + tid; i2 < P; i2 += 1024) cand[i2] = FLT_MAX;
    __syncthreads();
    for (int k = 2; k <= P; k <<= 1){
      for (int st = k >> 1; st > 0; st >>= 1){
        for (int i2 = tid; i2 < P; i2 += 1024){
          int j2 = i2 ^ st;
          if (j2 > i2){
            float a2 = cand[i2], b3 = cand[j2];
            bool up = ((i2 & k) == 0);
            if (up ? (a2 > b3) : (a2 < b3)){ cand[i2] = b3; cand[j2] = a2; }
          }
        }
        __syncthreads();
      }
    }
    if (tid == 0){
      float v1 = cand[2047 - cntBefore], v2 = cand[2048 - cntBefore];
      float med = 0.5f * (v1 + v2);
      astore(denom, 2.0f * med * med + 1e-8f);
    }
  }

  __syncthreads();
  if (tid == 0) gbar_leader(garr, gcnt, gen, 2);
  __syncthreads();

  // ---------- P2: CSR fill + per-row coef ----------
  if (e < N_Q * KNN){
    const int i = e / KNN, tt = e % KNN;
    const int j = nbr[e];
    const float wgt = aload(&wh[e]);
    const int p = aloadi(&rowptr[i]) + tt;
    colA[p] = j * N_C; wA[p] = wgt;
    const int q = aloadi(&rowptr[j]) + KNN + atomicAdd(&fillc[j], 1);
    colA[q] = i * N_C; wA[q] = wgt;
  }
  const float cf = expf(-d2m / aload(denom)) / (aload(&rowsum[row]) + 1e-8f);
  const int p0  = aloadi(&rowptr[row]);
  const int p1v = aloadi(&rowptr[row + 1]);

  // one-time flush+invalidate so colA/wA are plain-cacheable hereafter;
  // barrier 3 also guarantees every row's y0 is globally visible.
  __builtin_amdgcn_fence(__ATOMIC_RELEASE, "agent");
  __syncthreads();
  if (tid == 0) gbar_leader(garr, gcnt, gen, 3);
  __syncthreads();
  __builtin_amdgcn_fence(__ATOMIC_ACQUIRE, "agent");

  // ---------- P3: y1 = step(y0); publish delta via pbar phase 1 ----------
  float cur;
  {
    float s0=0.f,s1=0.f,s2=0.f,s3=0.f,s4=0.f,s5=0.f,s6=0.f,s7=0.f;
    int q = p0;
    for (; q + 8 <= p1v; q += 8){
      s0 = fmaf(wA[q    ], aload(&buf0[colA[q    ] + lane]), s0);
      s1 = fmaf(wA[q + 1], aload(&buf0[colA[q + 1] + lane]), s1);
      s2 = fmaf(wA[q + 2], aload(&buf0[colA[q + 2] + lane]), s2);
      s3 = fmaf(wA[q + 3], aload(&buf0[colA[q + 3] + lane]), s3);
      s4 = fmaf(wA[q + 4], aload(&buf0[colA[q + 4] + lane]), s4);
      s5 = fmaf(wA[q + 5], aload(&buf0[colA[q + 5] + lane]), s5);
      s6 = fmaf(wA[q + 6], aload(&buf0[colA[q + 6] + lane]), s6);
      s7 = fmaf(wA[q + 7], aload(&buf0[colA[q + 7] + lane]), s7);
    }
    for (; q < p1v; q++) s0 = fmaf(wA[q], aload(&buf0[colA[q] + lane]), s0);
    float xv2 = -av + cf * (((s0+s1)+(s2+s3)) + ((s4+s5)+(s6+s7)));
    float mm = wave_max64(xv2), e2 = expf(xv2 - mm), ss2 = wave_sum64(e2);
    cur = e2 / ss2;
    astore(&buf1[row * N_C + lane], cur);
  }
  float dm = wave_max64(fabsf(cur - prev));
  if (lane == 0) atomicMax(&sdm[1], __float_as_int(dm));
  __syncthreads();                         // drains all waves' y stores + LDS
  if (wv == 0) pbar_wave0(bflag, bdelta, 1, sdm, &sdelta, lane);
  __syncthreads();
  float delta = sdelta;

  // ---------- P4: the while-loop (R8 semantics) ----------
  int par = 1;                             // buffer currently holding y_new
  for (int t = 0;; t++){
    if (t >= MAX_ITER || delta < EPS_CONV) break;
    const float* src = par ? buf1 : buf0;
    float*       dst = par ? buf0 : buf1;
    float s0=0.f,s1=0.f,s2=0.f,s3=0.f,s4=0.f,s5=0.f,s6=0.f,s7=0.f;
    int q = p0;
    for (; q + 8 <= p1v; q += 8){
      s0 = fmaf(wA[q    ], aload(&src[colA[q    ] + lane]), s0);
      s1 = fmaf(wA[q + 1], aload(&src[colA[q + 1] + lane]), s1);
      s2 = fmaf(wA[q + 2], aload(&src[colA[q + 2] + lane]), s2);
      s3 = fmaf(wA[q + 3], aload(&src[colA[q + 3] + lane]), s3);
      s4 = fmaf(wA[q + 4], aload(&src[colA[q + 4] + lane]), s4);
      s5 = fmaf(wA[q + 5], aload(&src[colA[q + 5] + lane]), s5);
      s6 = fmaf(wA[q + 6], aload(&src[colA[q + 6] + lane]), s6);
      s7 = fmaf(wA[q + 7], aload(&src[colA[q + 7] + lane]), s7);
    }
    for (; q < p1v; q++) s0 = fmaf(wA[q], aload(&src[colA[q] + lane]), s0);
    float xv2 = -av + cf * (((s0+s1)+(s2+s3)) + ((s4+s5)+(s6+s7)));
    float mm = wave_max64(xv2), e2 = expf(xv2 - mm), ss2 = wave_sum64(e2);
    float nxt = e2 / ss2;
    astore(&dst[row * N_C + lane], nxt);
    const int ph = t + 2;
    dm = wave_max64(fabsf(nxt - cur));
    if (lane == 0) atomicMax(&sdm[ph & 1], __float_as_int(dm));
    __syncthreads();
    if (wv == 0) pbar_wave0(bflag, bdelta, ph, sdm, &sdelta, lane);
    __syncthreads();
    delta = sdelta;
    prev = cur; cur = nxt; par ^= 1;
  }

  // argmax of y (prev); first occurrence on ties
  float bv = prev; int bi = lane;
  #pragma unroll
  for (int o = 32; o; o >>= 1){
    float ov = __shfl_xor(bv, o, 64); int oi = __shfl_xor(bi, o, 64);
    if (ov > bv || (ov == bv && oi < bi)){ bv = ov; bi = oi; }
  }
  if (lane == 0) out[row] = bi;
}

extern "C" void kernel_launch(void* const* d_in, const int* in_sizes, int n_in,
                              void* d_out, int out_size, void* d_ws, size_t ws_size,
                              hipStream_t stream)
{
  const float* feat_s = (const float*)d_in[0];
  const int*   y_s    = (const int*)d_in[1];
  const float* feat_q = (const float*)d_in[2];
  int* out = (int*)d_out;

  char* wp = (char*)d_ws;
  auto alloc = [&](size_t bytes) -> char* {
    char* p = wp;
    wp += (bytes + 255) & ~(size_t)255;
    return p;
  };
  float*     Dq  = (float*)alloc((size_t)N_Q * N_Q * 4);     // 64 MB
  _Float16*  Xh  = (_Float16*)alloc((size_t)N_Q * DIM * 2);  // 8 MB
  _Float16*  Xl  = (_Float16*)alloc((size_t)N_Q * DIM * 2);  // 8 MB
  float* Pt     = (float*)alloc((size_t)DIM * N_C * 4);
  float* pn     = (float*)alloc(N_C * 4);
  float* qn     = (float*)alloc(N_Q * 4);
  float* d2min  = (float*)alloc(N_Q * 4);
  float* denom  = (float*)alloc(256);
  int*   nbr    = (int*)alloc((size_t)N_Q * KNN * 4);
  float* dnbr   = (float*)alloc((size_t)N_Q * KNN * 4);
  float* sigma  = (float*)alloc(N_Q * 4);
  float* wh     = (float*)alloc((size_t)N_Q * KNN * 4);
  int*   rowptr = (int*)alloc((N_Q + 1) * 4);
  int*   colA   = (int*)alloc((size_t)2 * N_Q * KNN * 4);
  float* wA     = (float*)alloc((size_t)2 * N_Q * KNN * 4);
  float* buf0   = (float*)alloc((size_t)N_Q * N_C * 4);
  float* buf1   = (float*)alloc((size_t)N_Q * N_C * 4);
  // zero-region: rowsum | indeg | fillc | syncw | garr | bflag | bdelta
  const size_t zbytes = (size_t)N_Q*12 + 256 + 2048 + 32768 + 65536;
  char*  zbase  = alloc(zbytes);
  float* rowsum = (float*)(zbase);
  int*   indeg  = (int*)(zbase + N_Q*4);
  int*   fillc  = (int*)(zbase + N_Q*8);
  int*   syncw  = (int*)(zbase + N_Q*12);
  int*   garr   = (int*)(zbase + N_Q*12 + 256);
  int*   bflag  = (int*)(zbase + N_Q*12 + 256 + 2048);
  int*   bdelta = (int*)(zbase + N_Q*12 + 256 + 2048 + 32768);

  hipMemsetAsync(zbase, 0, zbytes, stream);

  proto_kernel <<<N_C, 256, 0, stream>>>(feat_s, y_s, Pt, pn);
  prep_kernel  <<<N_Q, 256, 0, stream>>>(feat_q, qn, Xh, Xl);
  dist_mfma    <<<dim3(N_Q/128, N_Q/128), 256, 0, stream>>>(Xh, Xl, qn, Dq);
  topk_kernel  <<<N_Q, 256, 0, stream>>>(Dq, nbr, dnbr, sigma);

  int* gcnt = &syncw[0];
  int* gen  = &syncw[32];
  const float* Xq = feat_q;
  void* args[] = {&Xq, &Pt, &pn, &qn, &nbr, &dnbr, &sigma,
                  &d2min, &denom, &wh, &rowsum, &indeg, &rowptr, &fillc,
                  &colA, &wA, &buf0, &buf1, &bflag, &bdelta,
                  &gcnt, &gen, &garr, &out};
  hipLaunchCooperativeKernel((void*)tail_loop, dim3(NBLK), dim3(1024), args, 0, stream);
}

// Round 12
// 761.356 us; speedup vs baseline: 1.2105x; 1.0026x over previous
//
#include <hip/hip_runtime.h>
#include <hip/hip_cooperative_groups.h>
#include <cfloat>
#include <cmath>

#define N_Q 4096
#define N_S 1600
#define DIM 1024
#define N_C 64
#define KNN 12
#define MAX_ITER 50
#define EPS_CONV 1e-4f
#define NBLK 256         // tail_loop grid size

typedef _Float16 h8 __attribute__((ext_vector_type(8)));
typedef float    f4 __attribute__((ext_vector_type(4)));

__device__ __forceinline__ float wave_max64(float v){
  #pragma unroll
  for (int o = 32; o; o >>= 1) v = fmaxf(v, __shfl_xor(v, o, 64));
  return v;
}
__device__ __forceinline__ float wave_sum64(float v){
  #pragma unroll
  for (int o = 32; o; o >>= 1) v += __shfl_xor(v, o, 64);
  return v;
}
__device__ __forceinline__ float wave_min64(float v){
  #pragma unroll
  for (int o = 32; o; o >>= 1) v = fminf(v, __shfl_xor(v, o, 64));
  return v;
}

// coherent (device-visible) element accesses for cross-block-communicated data
__device__ __forceinline__ float aload(const float* p){
  return __hip_atomic_load(p, __ATOMIC_RELAXED, __HIP_MEMORY_SCOPE_AGENT);
}
__device__ __forceinline__ void astore(float* p, float v){
  __hip_atomic_store(p, v, __ATOMIC_RELAXED, __HIP_MEMORY_SCOPE_AGENT);
}
__device__ __forceinline__ int aloadi(const int* p){
  return __hip_atomic_load(p, __ATOMIC_RELAXED, __HIP_MEMORY_SCOPE_AGENT);
}
__device__ __forceinline__ void astorei(int* p, int v){
  __hip_atomic_store(p, v, __ATOMIC_RELAXED, __HIP_MEMORY_SCOPE_AGENT);
}

// ---- prototypes: segment mean, stored TRANSPOSED Pt[f][c]; per-class sqnorm.
__global__ __launch_bounds__(256) void proto_kernel(
    const float* __restrict__ fs, const int* __restrict__ ys,
    float* __restrict__ Pt, float* __restrict__ pn)
{
  const int c = blockIdx.x, t = threadIdx.x;
  float a0 = 0.f, a1 = 0.f, a2 = 0.f, a3 = 0.f;
  int cnt = 0;
  for (int i = 0; i < N_S; i++){
    if (ys[i] == c){
      const float* r = fs + (size_t)i * DIM;
      a0 += r[t]; a1 += r[t + 256]; a2 += r[t + 512]; a3 += r[t + 768];
      cnt++;
    }
  }
  const float inv = 1.0f / fmaxf((float)cnt, 1.0f);
  const float v0 = a0*inv, v1 = a1*inv, v2 = a2*inv, v3 = a3*inv;
  Pt[(t      )*N_C + c] = v0;
  Pt[(t + 256)*N_C + c] = v1;
  Pt[(t + 512)*N_C + c] = v2;
  Pt[(t + 768)*N_C + c] = v3;
  __shared__ float red[256];
  red[t] = v0*v0 + v1*v1 + v2*v2 + v3*v3;
  __syncthreads();
  for (int o = 128; o; o >>= 1){ if (t < o) red[t] += red[t + o]; __syncthreads(); }
  if (t == 0) pn[c] = red[0];
}

// ---- fused per-row sqnorm + fp32 -> (f16 hi, f16 lo) split.
__global__ __launch_bounds__(256) void prep_kernel(
    const float* __restrict__ X, float* __restrict__ qn,
    _Float16* __restrict__ Xh, _Float16* __restrict__ Xl)
{
  const int i = blockIdx.x, t = threadIdx.x;
  const float* r = X + (size_t)i * DIM;
  const float v0 = r[t], v1 = r[t+256], v2 = r[t+512], v3 = r[t+768];
  const size_t b = (size_t)i * DIM;
  _Float16 h0 = (_Float16)v0, h1 = (_Float16)v1, h2 = (_Float16)v2, h3 = (_Float16)v3;
  Xh[b + t      ] = h0; Xl[b + t      ] = (_Float16)(v0 - (float)h0);
  Xh[b + t + 256] = h1; Xl[b + t + 256] = (_Float16)(v1 - (float)h1);
  Xh[b + t + 512] = h2; Xl[b + t + 512] = (_Float16)(v2 - (float)h2);
  Xh[b + t + 768] = h3; Xl[b + t + 768] = (_Float16)(v3 - (float)h3);
  __shared__ float red[256];
  red[t] = v0*v0 + v1*v1 + v2*v2 + v3*v3;
  __syncthreads();
  for (int o = 128; o; o >>= 1){ if (t < o) red[t] += red[t + o]; __syncthreads(); }
  if (t == 0) qn[i] = red[0];
}

// ---- pairwise distances via f16 split-precision MFMA, R12: SOFTWARE-
//      PIPELINED K-loop. R11's loop loaded B frags per-sn and consumed them
//      immediately -> compiler waitcnt per sn-group -> ~4 serialized L3
//      round-trips per k0 step (16 MB split arrays miss the 4 MB per-XCD L2)
//      -> ~15% MFMA util. Now: two STATIC register stage-sets (no dynamic
//      reg indexing -> no scratch), k0 unrolled x2; all 16 loads of the next
//      32-chunk are issued before the current chunk's 48 MFMAs. MFMA order
//      within each chunk is unchanged (sn outer, sm inner, hh/hl/lh) ->
//      accumulators bit-identical to R11.
#define LOAD_STAGE(AH, AL, BH, BL, KK)                      \
  { _Pragma("unroll")                                       \
    for (int sm = 0; sm < 4; sm++){                         \
      const size_t o = (size_t)(sm * 16) * DIM + (KK);      \
      AH[sm] = *(const h8*)(pAh + o);                       \
      AL[sm] = *(const h8*)(pAl + o);                       \
      BH[sm] = *(const h8*)(pBh + o);                       \
      BL[sm] = *(const h8*)(pBl + o);                       \
    } }

#define MFMA_STAGE(AH, AL, BH, BL)                                                        \
  { _Pragma("unroll")                                                                     \
    for (int sn = 0; sn < 4; sn++){                                                       \
      _Pragma("unroll")                                                                   \
      for (int sm = 0; sm < 4; sm++){                                                     \
        acc[sm][sn] = __builtin_amdgcn_mfma_f32_16x16x32_f16(AH[sm], BH[sn], acc[sm][sn], 0, 0, 0); \
        acc[sm][sn] = __builtin_amdgcn_mfma_f32_16x16x32_f16(AH[sm], BL[sn], acc[sm][sn], 0, 0, 0); \
        acc[sm][sn] = __builtin_amdgcn_mfma_f32_16x16x32_f16(AL[sm], BH[sn], acc[sm][sn], 0, 0, 0); \
      } } }

__global__ __launch_bounds__(256, 2) void dist_mfma(
    const _Float16* __restrict__ Xh, const _Float16* __restrict__ Xl,
    const float* __restrict__ qn, float* __restrict__ Dq)
{
  const int t = threadIdx.x, w = t >> 6, l = t & 63;
  const int i0 = blockIdx.y * 128 + (w >> 1) * 64;
  const int j0 = blockIdx.x * 128 + (w & 1) * 64;
  const int fr = l & 15;
  const int kq = (l >> 4) * 8;

  f4 acc[4][4];
  #pragma unroll
  for (int a = 0; a < 4; a++)
    #pragma unroll
    for (int b = 0; b < 4; b++) acc[a][b] = (f4){0.f, 0.f, 0.f, 0.f};

  const _Float16* pAh = Xh + (size_t)(i0 + fr) * DIM + kq;
  const _Float16* pAl = Xl + (size_t)(i0 + fr) * DIM + kq;
  const _Float16* pBh = Xh + (size_t)(j0 + fr) * DIM + kq;
  const _Float16* pBl = Xl + (size_t)(j0 + fr) * DIM + kq;

  h8 ahA[4], alA[4], bhA[4], blA[4];
  h8 ahB[4], alB[4], bhB[4], blB[4];

  LOAD_STAGE(ahA, alA, bhA, blA, 0);
  #pragma unroll 1
  for (int k0 = 0; k0 < DIM; k0 += 64){
    LOAD_STAGE(ahB, alB, bhB, blB, k0 + 32);     // k0+32 <= 992 < DIM always
    MFMA_STAGE(ahA, alA, bhA, blA);
    if (k0 + 64 < DIM){
      LOAD_STAGE(ahA, alA, bhA, blA, k0 + 64);
    }
    MFMA_STAGE(ahB, alB, bhB, blB);
  }

  const int cr = (l >> 4) * 4;
  const int cc = l & 15;
  #pragma unroll
  for (int sm = 0; sm < 4; sm++){
    #pragma unroll
    for (int r = 0; r < 4; r++){
      const int row = i0 + sm * 16 + cr + r;
      const float qi = qn[row];
      float* dstrow = &Dq[(size_t)row * N_Q];
      #pragma unroll
      for (int sn = 0; sn < 4; sn++){
        const int col = j0 + sn * 16 + cc;
        float d2 = qi + qn[col] - 2.0f * acc[sm][sn][r];
        dstrow[col] = sqrtf(fmaxf(d2, 0.f));
      }
    }
  }
}

// ---- per-row 13 smallest (ties -> smaller index), row in registers.
__global__ __launch_bounds__(256) void topk_kernel(
    const float* __restrict__ Dq, int* __restrict__ nbr,
    float* __restrict__ dnbr, float* __restrict__ sigma)
{
  const int i = blockIdx.x, t = threadIdx.x;
  const float* row = Dq + (size_t)i * N_Q;
  float r[16];
  #pragma unroll
  for (int u = 0; u < 16; u++) r[u] = row[t + u * 256];

  __shared__ float pvf[4];
  __shared__ int   pif[4];
  __shared__ int   bwi_s;

  for (int s = 0; s < KNN + 1; s++){
    float best = FLT_MAX; int bj = 0x7fffffff;
    #pragma unroll
    for (int u = 0; u < 16; u++){
      float v = r[u];
      if (v < best){ best = v; bj = t + u * 256; }
    }
    #pragma unroll
    for (int o = 32; o; o >>= 1){
      float ov = __shfl_xor(best, o, 64); int oj = __shfl_xor(bj, o, 64);
      if (ov < best || (ov == best && oj < bj)){ best = ov; bj = oj; }
    }
    if ((t & 63) == 0){ pvf[t >> 6] = best; pif[t >> 6] = bj; }
    __syncthreads();
    if (t == 0){
      float bv = pvf[0]; int bi2 = pif[0];
      #pragma unroll
      for (int w2 = 1; w2 < 4; w2++){
        float v2 = pvf[w2]; int i2 = pif[w2];
        if (v2 < bv || (v2 == bv && i2 < bi2)){ bv = v2; bi2 = i2; }
      }
      bwi_s = bi2;
      if (s >= 1){ nbr[i*KNN + s - 1] = bi2; dnbr[i*KNN + s - 1] = bv; }
      if (s == KNN) sigma[i] = bv + 1e-8f;
    }
    __syncthreads();
    const int widx = bwi_s;
    if ((widx & 255) == t) r[widx >> 8] = FLT_MAX;
  }
}

// ============ hierarchical monotonic grid barrier (setup phases only) ============
__device__ __forceinline__ void gbar_leader(int* garr, int* gcnt, int* gen, int target){
  const int g = blockIdx.x >> 4;
  int old = __hip_atomic_fetch_add(&garr[g * 32], 1, __ATOMIC_RELAXED, __HIP_MEMORY_SCOPE_AGENT);
  if ((old & 15) == 15){
    int o2 = __hip_atomic_fetch_add(gcnt, 1, __ATOMIC_RELAXED, __HIP_MEMORY_SCOPE_AGENT);
    if ((o2 & 15) == 15)
      __hip_atomic_fetch_add(gen, 1, __ATOMIC_RELAXED, __HIP_MEMORY_SCOPE_AGENT);
  }
  while (__hip_atomic_load(gen, __ATOMIC_RELAXED, __HIP_MEMORY_SCOPE_AGENT) < target)
    __builtin_amdgcn_s_sleep(1);
}

// ============ parallel-read flag barrier (loop phases; wave 0 only) ============
__device__ __forceinline__ void pbar_wave0(
    int* bflag, int* bdelta, int ph, int* sdm, float* sdelta_sh, int lane)
{
  if (lane == 0){
    int myd = sdm[ph & 1]; sdm[ph & 1] = 0;
    astorei(&bdelta[(blockIdx.x * 2 + (ph & 1)) * 32], myd);
    __builtin_amdgcn_s_waitcnt(0);            // delta (and all prior y stores) drained
    astorei(&bflag[blockIdx.x * 32], ph);
  }
  while (1){
    int mn = 0x7fffffff;
    #pragma unroll
    for (int u = 0; u < 4; u++){
      int f = aloadi(&bflag[(lane + u * 64) * 32]);
      mn = f < mn ? f : mn;
    }
    if (__all(mn >= ph)) break;
    __builtin_amdgcn_s_sleep(1);
  }
  int mx = 0;                                 // deltas nonneg -> int compare ok
  #pragma unroll
  for (int u = 0; u < 4; u++){
    int d = aloadi(&bdelta[((lane + u * 64) * 2 + (ph & 1)) * 32]);
    mx = d > mx ? d : mx;
  }
  #pragma unroll
  for (int o = 32; o; o >>= 1){ int ox = __shfl_xor(mx, o, 64); mx = ox > mx ? ox : mx; }
  if (lane == 0) *sdelta_sh = __int_as_float(mx);
}

// ---- fused tail (unchanged from R11: 300 us)
__global__ __launch_bounds__(1024, 4) void tail_loop(
    const float* __restrict__ Xq, const float* __restrict__ Pt,
    const float* __restrict__ pn, const float* __restrict__ qn,
    const int* __restrict__ nbr, const float* __restrict__ dnbr,
    const float* __restrict__ sigma,
    float* d2min, float* denom, float* wh,
    float* rowsum, int* indeg, int* rowptr, int* fillc,
    int* colA, float* wA, float* buf0, float* buf1,
    int* bflag, int* bdelta,
    int* gcnt, int* gen, int* garr, int* __restrict__ out)
{
  __shared__ int   sdm[2];
  __shared__ float sdelta;
  __shared__ int   ipart[1024];
  __shared__ int   hist[1024];
  __shared__ float cand[4096];
  __shared__ int   candn, b1s, b2s;

  const int tid  = threadIdx.x;
  const int lane = tid & 63;
  const int wv   = tid >> 6;
  const int row  = blockIdx.x * 16 + wv;
  if (tid == 0){ sdm[0] = 0; sdm[1] = 0; }

  // ---------- P0a: a-row (kept in registers) ----------
  const float* xr = Xq + (size_t)row * DIM;
  float dp[8];
  #pragma unroll
  for (int u = 0; u < 8; u++) dp[u] = 0.f;
  for (int f = 0; f < DIM; f += 8){
    #pragma unroll
    for (int u = 0; u < 8; u++)
      dp[u] = fmaf(xr[f + u], Pt[(f + u) * N_C + lane], dp[u]);
  }
  const float dot = ((dp[0]+dp[1])+(dp[2]+dp[3])) + ((dp[4]+dp[5])+(dp[6]+dp[7]));
  const float av  = fmaxf(qn[row] + pn[lane] - 2.0f * dot, 0.0f);
  const float d2m = wave_min64(av);
  if (lane == 0) astore(&d2min[row], d2m);

  // ---------- P0b: edge weights + degrees ----------
  const int e = blockIdx.x * 1024 + tid;
  if (e < N_Q * KNN){
    const int i = e / KNN;
    const int j = nbr[e];
    float wgt = 0.5f * expf(-dnbr[e] / (sigma[i] * sigma[j]));
    astore(&wh[e], wgt);
    atomicAdd(&rowsum[i], wgt);
    atomicAdd(&rowsum[j], wgt);
    atomicAdd(&indeg[j], 1);
  }

  __syncthreads();
  if (tid == 0) gbar_leader(garr, gcnt, gen, 1);
  __syncthreads();

  // ---------- P1: y0 + scan (block 0) + median (block 1) ----------
  float xv = -av;
  float m = wave_max64(xv), ee = expf(xv - m), ss = wave_sum64(ee);
  float prev = ee / ss;                    // y0
  astore(&buf0[row * N_C + lane], prev);

  if (blockIdx.x == 0){
    const int base = tid * 4;
    int c0 = aloadi(&indeg[base]),     c1 = aloadi(&indeg[base + 1]);
    int c2 = aloadi(&indeg[base + 2]), c3 = aloadi(&indeg[base + 3]);
    const int s4 = c0 + c1 + c2 + c3;
    ipart[tid] = s4;
    __syncthreads();
    for (int off = 1; off < 1024; off <<= 1){
      int v = (tid >= off) ? ipart[tid - off] : 0;
      __syncthreads();
      ipart[tid] += v;
      __syncthreads();
    }
    int run = ipart[tid] - s4;
    astorei(&rowptr[base    ], KNN * (base    ) + run); run += c0;
    astorei(&rowptr[base + 1], KNN * (base + 1) + run); run += c1;
    astorei(&rowptr[base + 2], KNN * (base + 2) + run); run += c2;
    astorei(&rowptr[base + 3], KNN * (base + 3) + run);
    if (tid == 1023) astorei(&rowptr[N_Q], KNN * N_Q + ipart[1023]);
  }
  if (blockIdx.x == 1){
    const int base = tid * 4;
    float dv[4];
    #pragma unroll
    for (int u = 0; u < 4; u++) dv[u] = sqrtf(aload(&d2min[base + u]));
    float mn = fminf(fminf(dv[0], dv[1]), fminf(dv[2], dv[3]));
    float mx = fmaxf(fmaxf(dv[0], dv[1]), fmaxf(dv[2], dv[3]));
    mn = wave_min64(mn); mx = wave_max64(mx);
    if (lane == 0){ cand[wv] = mn; cand[wv + 16] = mx; }
    __syncthreads();
    if (tid == 0){
      float a = cand[0], b = cand[16];
      for (int k = 1; k < 16; k++){ a = fminf(a, cand[k]); b = fmaxf(b, cand[16 + k]); }
      cand[32] = a; cand[33] = b;
    }
    __syncthreads();
    mn = cand[32]; mx = cand[33];
    const float rng = mx - mn;
    const float scale = (rng > 0.f) ? (1024.0f / rng) : 0.f;
    hist[tid] = 0;
    __syncthreads();
    int bidx[4];
    #pragma unroll
    for (int u = 0; u < 4; u++){
      int b = (int)((dv[u] - mn) * scale);
      b = b < 0 ? 0 : (b > 1023 ? 1023 : b);
      bidx[u] = b;
      atomicAdd(&hist[b], 1);
    }
    __syncthreads();
    for (int off = 1; off < 1024; off <<= 1){
      int v = (tid >= off) ? hist[tid - off] : 0;
      __syncthreads();
      hist[tid] += v;
      __syncthreads();
    }
    if (hist[tid] >= 2048 && (tid == 0 || hist[tid - 1] < 2048)) b1s = tid;
    if (hist[tid] >= 2049 && (tid == 0 || hist[tid - 1] < 2049)) b2s = tid;
    if (tid == 0) candn = 0;
    __syncthreads();
    const int b1 = b1s, b2 = b2s;
    const int cntBefore = (b1 > 0) ? hist[b1 - 1] : 0;
    #pragma unroll
    for (int u = 0; u < 4; u++){
      if (bidx[u] >= b1 && bidx[u] <= b2){
        int pos = atomicAdd(&candn, 1);
        cand[pos] = dv[u];
      }
    }
    __syncthreads();
    const int mcnt = candn;
    int P = 2; while (P < mcnt) P <<= 1;
    for (int i2 = mcnt + tid; i2 < P; i2 += 1024) cand[i2] = FLT_MAX;
    __syncthreads();
    for (int k = 2; k <= P; k <<= 1){
      for (int st = k >> 1; st > 0; st >>= 1){
        for (int i2 = tid; i2 < P; i2 += 1024){
          int j2 = i2 ^ st;
          if (j2 > i2){
            float a2 = cand[i2], b3 = cand[j2];
            bool up = ((i2 & k) == 0);
            if (up ? (a2 > b3) : (a2 < b3)){ cand[i2] = b3; cand[j2] = a2; }
          }
        }
        __syncthreads();
      }
    }
    if (tid == 0){
      float v1 = cand[2047 - cntBefore], v2 = cand[2048 - cntBefore];
      float med = 0.5f * (v1 + v2);
      astore(denom, 2.0f * med * med + 1e-8f);
    }
  }

  __syncthreads();
  if (tid == 0) gbar_leader(garr, gcnt, gen, 2);
  __syncthreads();

  // ---------- P2: CSR fill + per-row coef ----------
  if (e < N_Q * KNN){
    const int i = e / KNN, tt = e % KNN;
    const int j = nbr[e];
    const float wgt = aload(&wh[e]);
    const int p = aloadi(&rowptr[i]) + tt;
    colA[p] = j * N_C; wA[p] = wgt;
    const int q = aloadi(&rowptr[j]) + KNN + atomicAdd(&fillc[j], 1);
    colA[q] = i * N_C; wA[q] = wgt;
  }
  const float cf = expf(-d2m / aload(denom)) / (aload(&rowsum[row]) + 1e-8f);
  const int p0  = aloadi(&rowptr[row]);
  const int p1v = aloadi(&rowptr[row + 1]);

  __builtin_amdgcn_fence(__ATOMIC_RELEASE, "agent");
  __syncthreads();
  if (tid == 0) gbar_leader(garr, gcnt, gen, 3);
  __syncthreads();
  __builtin_amdgcn_fence(__ATOMIC_ACQUIRE, "agent");

  // ---------- P3: y1 = step(y0); publish delta via pbar phase 1 ----------
  float cur;
  {
    float s0=0.f,s1=0.f,s2=0.f,s3=0.f,s4=0.f,s5=0.f,s6=0.f,s7=0.f;
    int q = p0;
    for (; q + 8 <= p1v; q += 8){
      s0 = fmaf(wA[q    ], aload(&buf0[colA[q    ] + lane]), s0);
      s1 = fmaf(wA[q + 1], aload(&buf0[colA[q + 1] + lane]), s1);
      s2 = fmaf(wA[q + 2], aload(&buf0[colA[q + 2] + lane]), s2);
      s3 = fmaf(wA[q + 3], aload(&buf0[colA[q + 3] + lane]), s3);
      s4 = fmaf(wA[q + 4], aload(&buf0[colA[q + 4] + lane]), s4);
      s5 = fmaf(wA[q + 5], aload(&buf0[colA[q + 5] + lane]), s5);
      s6 = fmaf(wA[q + 6], aload(&buf0[colA[q + 6] + lane]), s6);
      s7 = fmaf(wA[q + 7], aload(&buf0[colA[q + 7] + lane]), s7);
    }
    for (; q < p1v; q++) s0 = fmaf(wA[q], aload(&buf0[colA[q] + lane]), s0);
    float xv2 = -av + cf * (((s0+s1)+(s2+s3)) + ((s4+s5)+(s6+s7)));
    float mm = wave_max64(xv2), e2 = expf(xv2 - mm), ss2 = wave_sum64(e2);
    cur = e2 / ss2;
    astore(&buf1[row * N_C + lane], cur);
  }
  float dm = wave_max64(fabsf(cur - prev));
  if (lane == 0) atomicMax(&sdm[1], __float_as_int(dm));
  __syncthreads();                         // drains all waves' y stores + LDS
  if (wv == 0) pbar_wave0(bflag, bdelta, 1, sdm, &sdelta, lane);
  __syncthreads();
  float delta = sdelta;

  // ---------- P4: the while-loop (R8 semantics) ----------
  int par = 1;                             // buffer currently holding y_new
  for (int t = 0;; t++){
    if (t >= MAX_ITER || delta < EPS_CONV) break;
    const float* src = par ? buf1 : buf0;
    float*       dst = par ? buf0 : buf1;
    float s0=0.f,s1=0.f,s2=0.f,s3=0.f,s4=0.f,s5=0.f,s6=0.f,s7=0.f;
    int q = p0;
    for (; q + 8 <= p1v; q += 8){
      s0 = fmaf(wA[q    ], aload(&src[colA[q    ] + lane]), s0);
      s1 = fmaf(wA[q + 1], aload(&src[colA[q + 1] + lane]), s1);
      s2 = fmaf(wA[q + 2], aload(&src[colA[q + 2] + lane]), s2);
      s3 = fmaf(wA[q + 3], aload(&src[colA[q + 3] + lane]), s3);
      s4 = fmaf(wA[q + 4], aload(&src[colA[q + 4] + lane]), s4);
      s5 = fmaf(wA[q + 5], aload(&src[colA[q + 5] + lane]), s5);
      s6 = fmaf(wA[q + 6], aload(&src[colA[q + 6] + lane]), s6);
      s7 = fmaf(wA[q + 7], aload(&src[colA[q + 7] + lane]), s7);
    }
    for (; q < p1v; q++) s0 = fmaf(wA[q], aload(&src[colA[q] + lane]), s0);
    float xv2 = -av + cf * (((s0+s1)+(s2+s3)) + ((s4+s5)+(s6+s7)));
    float mm = wave_max64(xv2), e2 = expf(xv2 - mm), ss2 = wave_sum64(e2);
    float nxt = e2 / ss2;
    astore(&dst[row * N_C + lane], nxt);
    const int ph = t + 2;
    dm = wave_max64(fabsf(nxt - cur));
    if (lane == 0) atomicMax(&sdm[ph & 1], __float_as_int(dm));
    __syncthreads();
    if (wv == 0) pbar_wave0(bflag, bdelta, ph, sdm, &sdelta, lane);
    __syncthreads();
    delta = sdelta;
    prev = cur; cur = nxt; par ^= 1;
  }

  // argmax of y (prev); first occurrence on ties
  float bv = prev; int bi = lane;
  #pragma unroll
  for (int o = 32; o; o >>= 1){
    float ov = __shfl_xor(bv, o, 64); int oi = __shfl_xor(bi, o, 64);
    if (ov > bv || (ov == bv && oi < bi)){ bv = ov; bi = oi; }
  }
  if (lane == 0) out[row] = bi;
}

extern "C" void kernel_launch(void* const* d_in, const int* in_sizes, int n_in,
                              void* d_out, int out_size, void* d_ws, size_t ws_size,
                              hipStream_t stream)
{
  const float* feat_s = (const float*)d_in[0];
  const int*   y_s    = (const int*)d_in[1];
  const float* feat_q = (const float*)d_in[2];
  int* out = (int*)d_out;

  char* wp = (char*)d_ws;
  auto alloc = [&](size_t bytes) -> char* {
    char* p = wp;
    wp += (bytes + 255) & ~(size_t)255;
    return p;
  };
  float*     Dq  = (float*)alloc((size_t)N_Q * N_Q * 4);     // 64 MB
  _Float16*  Xh  = (_Float16*)alloc((size_t)N_Q * DIM * 2);  // 8 MB
  _Float16*  Xl  = (_Float16*)alloc((size_t)N_Q * DIM * 2);  // 8 MB
  float* Pt     = (float*)alloc((size_t)DIM * N_C * 4);
  float* pn     = (float*)alloc(N_C * 4);
  float* qn     = (float*)alloc(N_Q * 4);
  float* d2min  = (float*)alloc(N_Q * 4);
  float* denom  = (float*)alloc(256);
  int*   nbr    = (int*)alloc((size_t)N_Q * KNN * 4);
  float* dnbr   = (float*)alloc((size_t)N_Q * KNN * 4);
  float* sigma  = (float*)alloc(N_Q * 4);
  float* wh     = (float*)alloc((size_t)N_Q * KNN * 4);
  int*   rowptr = (int*)alloc((N_Q + 1) * 4);
  int*   colA   = (int*)alloc((size_t)2 * N_Q * KNN * 4);
  float* wA     = (float*)alloc((size_t)2 * N_Q * KNN * 4);
  float* buf0   = (float*)alloc((size_t)N_Q * N_C * 4);
  float* buf1   = (float*)alloc((size_t)N_Q * N_C * 4);
  // zero-region: rowsum | indeg | fillc | syncw | garr | bflag | bdelta
  const size_t zbytes = (size_t)N_Q*12 + 256 + 2048 + 32768 + 65536;
  char*  zbase  = alloc(zbytes);
  float* rowsum = (float*)(zbase);
  int*   indeg  = (int*)(zbase + N_Q*4);
  int*   fillc  = (int*)(zbase + N_Q*8);
  int*   syncw  = (int*)(zbase + N_Q*12);
  int*   garr   = (int*)(zbase + N_Q*12 + 256);
  int*   bflag  = (int*)(zbase + N_Q*12 + 256 + 2048);
  int*   bdelta = (int*)(zbase + N_Q*12 + 256 + 2048 + 32768);

  hipMemsetAsync(zbase, 0, zbytes, stream);

  proto_kernel <<<N_C, 256, 0, stream>>>(feat_s, y_s, Pt, pn);
  prep_kernel  <<<N_Q, 256, 0, stream>>>(feat_q, qn, Xh, Xl);
  dist_mfma    <<<dim3(N_Q/128, N_Q/128), 256, 0, stream>>>(Xh, Xl, qn, Dq);
  topk_kernel  <<<N_Q, 256, 0, stream>>>(Dq, nbr, dnbr, sigma);

  int* gcnt = &syncw[0];
  int* gen  = &syncw[32];
  const float* Xq = feat_q;
  void* args[] = {&Xq, &Pt, &pn, &qn, &nbr, &dnbr, &sigma,
                  &d2min, &denom, &wh, &rowsum, &indeg, &rowptr, &fillc,
                  &colA, &wA, &buf0, &buf1, &bflag, &bdelta,
                  &gcnt, &gen, &garr, &out};
  hipLaunchCooperativeKernel((void*)tail_loop, dim3(NBLK), dim3(1024), args, 0, stream);
}

// Round 13
// 698.377 us; speedup vs baseline: 1.3196x; 1.0902x over previous
//
#include <hip/hip_runtime.h>
#include <hip/hip_cooperative_groups.h>
#include <cfloat>
#include <cmath>

#define N_Q 4096
#define N_S 1600
#define DIM 1024
#define N_C 64
#define KNN 12
#define MAX_ITER 50
#define EPS_CONV 1e-4f
#define NBLK 256         // tail_loop grid size

typedef _Float16 h8 __attribute__((ext_vector_type(8)));
typedef float    f4 __attribute__((ext_vector_type(4)));

__device__ __forceinline__ float wave_max64(float v){
  #pragma unroll
  for (int o = 32; o; o >>= 1) v = fmaxf(v, __shfl_xor(v, o, 64));
  return v;
}
__device__ __forceinline__ float wave_sum64(float v){
  #pragma unroll
  for (int o = 32; o; o >>= 1) v += __shfl_xor(v, o, 64);
  return v;
}
__device__ __forceinline__ float wave_min64(float v){
  #pragma unroll
  for (int o = 32; o; o >>= 1) v = fminf(v, __shfl_xor(v, o, 64));
  return v;
}

// coherent (device-visible) element accesses for cross-block-communicated data
__device__ __forceinline__ float aload(const float* p){
  return __hip_atomic_load(p, __ATOMIC_RELAXED, __HIP_MEMORY_SCOPE_AGENT);
}
__device__ __forceinline__ void astore(float* p, float v){
  __hip_atomic_store(p, v, __ATOMIC_RELAXED, __HIP_MEMORY_SCOPE_AGENT);
}
__device__ __forceinline__ int aloadi(const int* p){
  return __hip_atomic_load(p, __ATOMIC_RELAXED, __HIP_MEMORY_SCOPE_AGENT);
}
__device__ __forceinline__ void astorei(int* p, int v){
  __hip_atomic_store(p, v, __ATOMIC_RELAXED, __HIP_MEMORY_SCOPE_AGENT);
}

// ---- prototypes, R13 rewrite: the old kernel ran a SERIAL 1600-iteration
//      loop per class (64 blocks only, branch on just-loaded ys[i] ->
//      latency-bound, est. 40-130 us). Now: parallel ORDERED compaction
//      (contiguous 7-sample segments + LDS prefix scan -> ascending match
//      list, ~25 entries), then accumulate over matches only. Per-feature
//      add order = ascending sample index, identical to before -> bit-exact.
__global__ __launch_bounds__(256) void proto_kernel(
    const float* __restrict__ fs, const int* __restrict__ ys,
    float* __restrict__ Pt, float* __restrict__ pn)
{
  const int c = blockIdx.x, t = threadIdx.x;
  __shared__ int list[N_S];
  __shared__ int pref[256];
  __shared__ int lcount;

  int loc[7]; int cnt = 0;
  const int base = t * 7;                  // 256*7 = 1792 >= 1600
  #pragma unroll
  for (int u = 0; u < 7; u++){
    const int i = base + u;
    if (i < N_S && ys[i] == c) loc[cnt++] = i;
  }
  pref[t] = cnt;
  __syncthreads();
  for (int off = 1; off < 256; off <<= 1){
    int v = (t >= off) ? pref[t - off] : 0;
    __syncthreads();
    pref[t] += v;
    __syncthreads();
  }
  const int start = pref[t] - cnt;
  for (int u = 0; u < cnt; u++) list[start + u] = loc[u];
  if (t == 255) lcount = pref[255];
  __syncthreads();

  const int n = lcount;
  float a0 = 0.f, a1 = 0.f, a2 = 0.f, a3 = 0.f;
  for (int m = 0; m < n; m++){
    const float* r = fs + (size_t)list[m] * DIM;
    a0 += r[t]; a1 += r[t + 256]; a2 += r[t + 512]; a3 += r[t + 768];
  }
  const float inv = 1.0f / fmaxf((float)n, 1.0f);
  const float v0 = a0*inv, v1 = a1*inv, v2 = a2*inv, v3 = a3*inv;
  Pt[(t      )*N_C + c] = v0;
  Pt[(t + 256)*N_C + c] = v1;
  Pt[(t + 512)*N_C + c] = v2;
  Pt[(t + 768)*N_C + c] = v3;
  __shared__ float red[256];
  red[t] = v0*v0 + v1*v1 + v2*v2 + v3*v3;
  __syncthreads();
  for (int o = 128; o; o >>= 1){ if (t < o) red[t] += red[t + o]; __syncthreads(); }
  if (t == 0) pn[c] = red[0];
}

// ---- fused per-row sqnorm + fp32 -> (f16 hi, f16 lo) split.
__global__ __launch_bounds__(256) void prep_kernel(
    const float* __restrict__ X, float* __restrict__ qn,
    _Float16* __restrict__ Xh, _Float16* __restrict__ Xl)
{
  const int i = blockIdx.x, t = threadIdx.x;
  const float* r = X + (size_t)i * DIM;
  const float v0 = r[t], v1 = r[t+256], v2 = r[t+512], v3 = r[t+768];
  const size_t b = (size_t)i * DIM;
  _Float16 h0 = (_Float16)v0, h1 = (_Float16)v1, h2 = (_Float16)v2, h3 = (_Float16)v3;
  Xh[b + t      ] = h0; Xl[b + t      ] = (_Float16)(v0 - (float)h0);
  Xh[b + t + 256] = h1; Xl[b + t + 256] = (_Float16)(v1 - (float)h1);
  Xh[b + t + 512] = h2; Xl[b + t + 512] = (_Float16)(v2 - (float)h2);
  Xh[b + t + 768] = h3; Xl[b + t + 768] = (_Float16)(v3 - (float)h3);
  __shared__ float red[256];
  red[t] = v0*v0 + v1*v1 + v2*v2 + v3*v3;
  __syncthreads();
  for (int o = 128; o; o >>= 1){ if (t < o) red[t] += red[t + o]; __syncthreads(); }
  if (t == 0) qn[i] = red[0];
}

// ---- pairwise distances via f16 split-precision MFMA. R13: back to the
//      R11 single-stage loop (R12's 2-stage pipeline was measured neutral ->
//      compiler already hoists loads), with __launch_bounds__(256,3):
//      ~140 VGPR fits the 170 cap -> 3 blocks/CU instead of 2 (+50% latency
//      hiding). If this spills, dist will show in top-5 with WRITE blowup.
//      MFMA order per (sm,sn,k) unchanged -> accumulators bit-identical.
__global__ __launch_bounds__(256, 3) void dist_mfma(
    const _Float16* __restrict__ Xh, const _Float16* __restrict__ Xl,
    const float* __restrict__ qn, float* __restrict__ Dq)
{
  const int t = threadIdx.x, w = t >> 6, l = t & 63;
  const int i0 = blockIdx.y * 128 + (w >> 1) * 64;
  const int j0 = blockIdx.x * 128 + (w & 1) * 64;
  const int fr = l & 15;
  const int kq = (l >> 4) * 8;

  f4 acc[4][4];
  #pragma unroll
  for (int a = 0; a < 4; a++)
    #pragma unroll
    for (int b = 0; b < 4; b++) acc[a][b] = (f4){0.f, 0.f, 0.f, 0.f};

  const _Float16* pAh = Xh + (size_t)(i0 + fr) * DIM + kq;
  const _Float16* pAl = Xl + (size_t)(i0 + fr) * DIM + kq;
  const _Float16* pBh = Xh + (size_t)(j0 + fr) * DIM + kq;
  const _Float16* pBl = Xl + (size_t)(j0 + fr) * DIM + kq;

  #pragma unroll 1
  for (int k0 = 0; k0 < DIM; k0 += 32){
    h8 ah[4], al[4];
    #pragma unroll
    for (int sm = 0; sm < 4; sm++){
      const size_t o = (size_t)(sm * 16) * DIM + k0;
      ah[sm] = *(const h8*)(pAh + o);
      al[sm] = *(const h8*)(pAl + o);
    }
    #pragma unroll
    for (int sn = 0; sn < 4; sn++){
      const size_t o = (size_t)(sn * 16) * DIM + k0;
      h8 bh = *(const h8*)(pBh + o);
      h8 bl = *(const h8*)(pBl + o);
      #pragma unroll
      for (int sm = 0; sm < 4; sm++){
        acc[sm][sn] = __builtin_amdgcn_mfma_f32_16x16x32_f16(ah[sm], bh, acc[sm][sn], 0, 0, 0);
        acc[sm][sn] = __builtin_amdgcn_mfma_f32_16x16x32_f16(ah[sm], bl, acc[sm][sn], 0, 0, 0);
        acc[sm][sn] = __builtin_amdgcn_mfma_f32_16x16x32_f16(al[sm], bh, acc[sm][sn], 0, 0, 0);
      }
    }
  }

  const int cr = (l >> 4) * 4;
  const int cc = l & 15;
  #pragma unroll
  for (int sm = 0; sm < 4; sm++){
    #pragma unroll
    for (int r = 0; r < 4; r++){
      const int row = i0 + sm * 16 + cr + r;
      const float qi = qn[row];
      float* dstrow = &Dq[(size_t)row * N_Q];
      #pragma unroll
      for (int sn = 0; sn < 4; sn++){
        const int col = j0 + sn * 16 + cc;
        float d2 = qi + qn[col] - 2.0f * acc[sm][sn][r];
        dstrow[col] = sqrtf(fmaxf(d2, 0.f));
      }
    }
  }
}

// ---- per-row 13 smallest (ties -> smaller index), row in registers.
__global__ __launch_bounds__(256) void topk_kernel(
    const float* __restrict__ Dq, int* __restrict__ nbr,
    float* __restrict__ dnbr, float* __restrict__ sigma)
{
  const int i = blockIdx.x, t = threadIdx.x;
  const float* row = Dq + (size_t)i * N_Q;
  float r[16];
  #pragma unroll
  for (int u = 0; u < 16; u++) r[u] = row[t + u * 256];

  __shared__ float pvf[4];
  __shared__ int   pif[4];
  __shared__ int   bwi_s;

  for (int s = 0; s < KNN + 1; s++){
    float best = FLT_MAX; int bj = 0x7fffffff;
    #pragma unroll
    for (int u = 0; u < 16; u++){
      float v = r[u];
      if (v < best){ best = v; bj = t + u * 256; }
    }
    #pragma unroll
    for (int o = 32; o; o >>= 1){
      float ov = __shfl_xor(best, o, 64); int oj = __shfl_xor(bj, o, 64);
      if (ov < best || (ov == best && oj < bj)){ best = ov; bj = oj; }
    }
    if ((t & 63) == 0){ pvf[t >> 6] = best; pif[t >> 6] = bj; }
    __syncthreads();
    if (t == 0){
      float bv = pvf[0]; int bi2 = pif[0];
      #pragma unroll
      for (int w2 = 1; w2 < 4; w2++){
        float v2 = pvf[w2]; int i2 = pif[w2];
        if (v2 < bv || (v2 == bv && i2 < bi2)){ bv = v2; bi2 = i2; }
      }
      bwi_s = bi2;
      if (s >= 1){ nbr[i*KNN + s - 1] = bi2; dnbr[i*KNN + s - 1] = bv; }
      if (s == KNN) sigma[i] = bv + 1e-8f;
    }
    __syncthreads();
    const int widx = bwi_s;
    if ((widx & 255) == t) r[widx >> 8] = FLT_MAX;
  }
}

// ============ hierarchical monotonic grid barrier (setup phases only) ============
__device__ __forceinline__ void gbar_leader(int* garr, int* gcnt, int* gen, int target){
  const int g = blockIdx.x >> 4;
  int old = __hip_atomic_fetch_add(&garr[g * 32], 1, __ATOMIC_RELAXED, __HIP_MEMORY_SCOPE_AGENT);
  if ((old & 15) == 15){
    int o2 = __hip_atomic_fetch_add(gcnt, 1, __ATOMIC_RELAXED, __HIP_MEMORY_SCOPE_AGENT);
    if ((o2 & 15) == 15)
      __hip_atomic_fetch_add(gen, 1, __ATOMIC_RELAXED, __HIP_MEMORY_SCOPE_AGENT);
  }
  while (__hip_atomic_load(gen, __ATOMIC_RELAXED, __HIP_MEMORY_SCOPE_AGENT) < target)
    __builtin_amdgcn_s_sleep(1);
}

// ============ parallel-read flag barrier (loop phases; wave 0 only) ============
__device__ __forceinline__ void pbar_wave0(
    int* bflag, int* bdelta, int ph, int* sdm, float* sdelta_sh, int lane)
{
  if (lane == 0){
    int myd = sdm[ph & 1]; sdm[ph & 1] = 0;
    astorei(&bdelta[(blockIdx.x * 2 + (ph & 1)) * 32], myd);
    __builtin_amdgcn_s_waitcnt(0);            // delta (and all prior y stores) drained
    astorei(&bflag[blockIdx.x * 32], ph);
  }
  while (1){
    int mn = 0x7fffffff;
    #pragma unroll
    for (int u = 0; u < 4; u++){
      int f = aloadi(&bflag[(lane + u * 64) * 32]);
      mn = f < mn ? f : mn;
    }
    if (__all(mn >= ph)) break;
    __builtin_amdgcn_s_sleep(1);
  }
  int mx = 0;                                 // deltas nonneg -> int compare ok
  #pragma unroll
  for (int u = 0; u < 4; u++){
    int d = aloadi(&bdelta[((lane + u * 64) * 2 + (ph & 1)) * 32]);
    mx = d > mx ? d : mx;
  }
  #pragma unroll
  for (int o = 32; o; o >>= 1){ int ox = __shfl_xor(mx, o, 64); mx = ox > mx ? ox : mx; }
  if (lane == 0) *sdelta_sh = __int_as_float(mx);
}

// ---- fused tail (unchanged from R11/R12: ~300 us)
__global__ __launch_bounds__(1024, 4) void tail_loop(
    const float* __restrict__ Xq, const float* __restrict__ Pt,
    const float* __restrict__ pn, const float* __restrict__ qn,
    const int* __restrict__ nbr, const float* __restrict__ dnbr,
    const float* __restrict__ sigma,
    float* d2min, float* denom, float* wh,
    float* rowsum, int* indeg, int* rowptr, int* fillc,
    int* colA, float* wA, float* buf0, float* buf1,
    int* bflag, int* bdelta,
    int* gcnt, int* gen, int* garr, int* __restrict__ out)
{
  __shared__ int   sdm[2];
  __shared__ float sdelta;
  __shared__ int   ipart[1024];
  __shared__ int   hist[1024];
  __shared__ float cand[4096];
  __shared__ int   candn, b1s, b2s;

  const int tid  = threadIdx.x;
  const int lane = tid & 63;
  const int wv   = tid >> 6;
  const int row  = blockIdx.x * 16 + wv;
  if (tid == 0){ sdm[0] = 0; sdm[1] = 0; }

  // ---------- P0a: a-row (kept in registers) ----------
  const float* xr = Xq + (size_t)row * DIM;
  float dp[8];
  #pragma unroll
  for (int u = 0; u < 8; u++) dp[u] = 0.f;
  for (int f = 0; f < DIM; f += 8){
    #pragma unroll
    for (int u = 0; u < 8; u++)
      dp[u] = fmaf(xr[f + u], Pt[(f + u) * N_C + lane], dp[u]);
  }
  const float dot = ((dp[0]+dp[1])+(dp[2]+dp[3])) + ((dp[4]+dp[5])+(dp[6]+dp[7]));
  const float av  = fmaxf(qn[row] + pn[lane] - 2.0f * dot, 0.0f);
  const float d2m = wave_min64(av);
  if (lane == 0) astore(&d2min[row], d2m);

  // ---------- P0b: edge weights + degrees ----------
  const int e = blockIdx.x * 1024 + tid;
  if (e < N_Q * KNN){
    const int i = e / KNN;
    const int j = nbr[e];
    float wgt = 0.5f * expf(-dnbr[e] / (sigma[i] * sigma[j]));
    astore(&wh[e], wgt);
    atomicAdd(&rowsum[i], wgt);
    atomicAdd(&rowsum[j], wgt);
    atomicAdd(&indeg[j], 1);
  }

  __syncthreads();
  if (tid == 0) gbar_leader(garr, gcnt, gen, 1);
  __syncthreads();

  // ---------- P1: y0 + scan (block 0) + median (block 1) ----------
  float xv = -av;
  float m = wave_max64(xv), ee = expf(xv - m), ss = wave_sum64(ee);
  float prev = ee / ss;                    // y0
  astore(&buf0[row * N_C + lane], prev);

  if (blockIdx.x == 0){
    const int base = tid * 4;
    int c0 = aloadi(&indeg[base]),     c1 = aloadi(&indeg[base + 1]);
    int c2 = aloadi(&indeg[base + 2]), c3 = aloadi(&indeg[base + 3]);
    const int s4 = c0 + c1 + c2 + c3;
    ipart[tid] = s4;
    __syncthreads();
    for (int off = 1; off < 1024; off <<= 1){
      int v = (tid >= off) ? ipart[tid - off] : 0;
      __syncthreads();
      ipart[tid] += v;
      __syncthreads();
    }
    int run = ipart[tid] - s4;
    astorei(&rowptr[base    ], KNN * (base    ) + run); run += c0;
    astorei(&rowptr[base + 1], KNN * (base + 1) + run); run += c1;
    astorei(&rowptr[base + 2], KNN * (base + 2) + run); run += c2;
    astorei(&rowptr[base + 3], KNN * (base + 3) + run);
    if (tid == 1023) astorei(&rowptr[N_Q], KNN * N_Q + ipart[1023]);
  }
  if (blockIdx.x == 1){
    const int base = tid * 4;
    float dv[4];
    #pragma unroll
    for (int u = 0; u < 4; u++) dv[u] = sqrtf(aload(&d2min[base + u]));
    float mn = fminf(fminf(dv[0], dv[1]), fminf(dv[2], dv[3]));
    float mx = fmaxf(fmaxf(dv[0], dv[1]), fmaxf(dv[2], dv[3]));
    mn = wave_min64(mn); mx = wave_max64(mx);
    if (lane == 0){ cand[wv] = mn; cand[wv + 16] = mx; }
    __syncthreads();
    if (tid == 0){
      float a = cand[0], b = cand[16];
      for (int k = 1; k < 16; k++){ a = fminf(a, cand[k]); b = fmaxf(b, cand[16 + k]); }
      cand[32] = a; cand[33] = b;
    }
    __syncthreads();
    mn = cand[32]; mx = cand[33];
    const float rng = mx - mn;
    const float scale = (rng > 0.f) ? (1024.0f / rng) : 0.f;
    hist[tid] = 0;
    __syncthreads();
    int bidx[4];
    #pragma unroll
    for (int u = 0; u < 4; u++){
      int b = (int)((dv[u] - mn) * scale);
      b = b < 0 ? 0 : (b > 1023 ? 1023 : b);
      bidx[u] = b;
      atomicAdd(&hist[b], 1);
    }
    __syncthreads();
    for (int off = 1; off < 1024; off <<= 1){
      int v = (tid >= off) ? hist[tid - off] : 0;
      __syncthreads();
      hist[tid] += v;
      __syncthreads();
    }
    if (hist[tid] >= 2048 && (tid == 0 || hist[tid - 1] < 2048)) b1s = tid;
    if (hist[tid] >= 2049 && (tid == 0 || hist[tid - 1] < 2049)) b2s = tid;
    if (tid == 0) candn = 0;
    __syncthreads();
    const int b1 = b1s, b2 = b2s;
    const int cntBefore = (b1 > 0) ? hist[b1 - 1] : 0;
    #pragma unroll
    for (int u = 0; u < 4; u++){
      if (bidx[u] >= b1 && bidx[u] <= b2){
        int pos = atomicAdd(&candn, 1);
        cand[pos] = dv[u];
      }
    }
    __syncthreads();
    const int mcnt = candn;
    int P = 2; while (P < mcnt) P <<= 1;
    for (int i2 = mcnt + tid; i2 < P; i2 += 1024) cand[i2] = FLT_MAX;
    __syncthreads();
    for (int k = 2; k <= P; k <<= 1){
      for (int st = k >> 1; st > 0; st >>= 1){
        for (int i2 = tid; i2 < P; i2 += 1024){
          int j2 = i2 ^ st;
          if (j2 > i2){
            float a2 = cand[i2], b3 = cand[j2];
            bool up = ((i2 & k) == 0);
            if (up ? (a2 > b3) : (a2 < b3)){ cand[i2] = b3; cand[j2] = a2; }
          }
        }
        __syncthreads();
      }
    }
    if (tid == 0){
      float v1 = cand[2047 - cntBefore], v2 = cand[2048 - cntBefore];
      float med = 0.5f * (v1 + v2);
      astore(denom, 2.0f * med * med + 1e-8f);
    }
  }

  __syncthreads();
  if (tid == 0) gbar_leader(garr, gcnt, gen, 2);
  __syncthreads();

  // ---------- P2: CSR fill + per-row coef ----------
  if (e < N_Q * KNN){
    const int i = e / KNN, tt = e % KNN;
    const int j = nbr[e];
    const float wgt = aload(&wh[e]);
    const int p = aloadi(&rowptr[i]) + tt;
    colA[p] = j * N_C; wA[p] = wgt;
    const int q = aloadi(&rowptr[j]) + KNN + atomicAdd(&fillc[j], 1);
    colA[q] = i * N_C; wA[q] = wgt;
  }
  const float cf = expf(-d2m / aload(denom)) / (aload(&rowsum[row]) + 1e-8f);
  const int p0  = aloadi(&rowptr[row]);
  const int p1v = aloadi(&rowptr[row + 1]);

  __builtin_amdgcn_fence(__ATOMIC_RELEASE, "agent");
  __syncthreads();
  if (tid == 0) gbar_leader(garr, gcnt, gen, 3);
  __syncthreads();
  __builtin_amdgcn_fence(__ATOMIC_ACQUIRE, "agent");

  // ---------- P3: y1 = step(y0); publish delta via pbar phase 1 ----------
  float cur;
  {
    float s0=0.f,s1=0.f,s2=0.f,s3=0.f,s4=0.f,s5=0.f,s6=0.f,s7=0.f;
    int q = p0;
    for (; q + 8 <= p1v; q += 8){
      s0 = fmaf(wA[q    ], aload(&buf0[colA[q    ] + lane]), s0);
      s1 = fmaf(wA[q + 1], aload(&buf0[colA[q + 1] + lane]), s1);
      s2 = fmaf(wA[q + 2], aload(&buf0[colA[q + 2] + lane]), s2);
      s3 = fmaf(wA[q + 3], aload(&buf0[colA[q + 3] + lane]), s3);
      s4 = fmaf(wA[q + 4], aload(&buf0[colA[q + 4] + lane]), s4);
      s5 = fmaf(wA[q + 5], aload(&buf0[colA[q + 5] + lane]), s5);
      s6 = fmaf(wA[q + 6], aload(&buf0[colA[q + 6] + lane]), s6);
      s7 = fmaf(wA[q + 7], aload(&buf0[colA[q + 7] + lane]), s7);
    }
    for (; q < p1v; q++) s0 = fmaf(wA[q], aload(&buf0[colA[q] + lane]), s0);
    float xv2 = -av + cf * (((s0+s1)+(s2+s3)) + ((s4+s5)+(s6+s7)));
    float mm = wave_max64(xv2), e2 = expf(xv2 - mm), ss2 = wave_sum64(e2);
    cur = e2 / ss2;
    astore(&buf1[row * N_C + lane], cur);
  }
  float dm = wave_max64(fabsf(cur - prev));
  if (lane == 0) atomicMax(&sdm[1], __float_as_int(dm));
  __syncthreads();                         // drains all waves' y stores + LDS
  if (wv == 0) pbar_wave0(bflag, bdelta, 1, sdm, &sdelta, lane);
  __syncthreads();
  float delta = sdelta;

  // ---------- P4: the while-loop (R8 semantics) ----------
  int par = 1;                             // buffer currently holding y_new
  for (int t = 0;; t++){
    if (t >= MAX_ITER || delta < EPS_CONV) break;
    const float* src = par ? buf1 : buf0;
    float*       dst = par ? buf0 : buf1;
    float s0=0.f,s1=0.f,s2=0.f,s3=0.f,s4=0.f,s5=0.f,s6=0.f,s7=0.f;
    int q = p0;
    for (; q + 8 <= p1v; q += 8){
      s0 = fmaf(wA[q    ], aload(&src[colA[q    ] + lane]), s0);
      s1 = fmaf(wA[q + 1], aload(&src[colA[q + 1] + lane]), s1);
      s2 = fmaf(wA[q + 2], aload(&src[colA[q + 2] + lane]), s2);
      s3 = fmaf(wA[q + 3], aload(&src[colA[q + 3] + lane]), s3);
      s4 = fmaf(wA[q + 4], aload(&src[colA[q + 4] + lane]), s4);
      s5 = fmaf(wA[q + 5], aload(&src[colA[q + 5] + lane]), s5);
      s6 = fmaf(wA[q + 6], aload(&src[colA[q + 6] + lane]), s6);
      s7 = fmaf(wA[q + 7], aload(&src[colA[q + 7] + lane]), s7);
    }
    for (; q < p1v; q++) s0 = fmaf(wA[q], aload(&src[colA[q] + lane]), s0);
    float xv2 = -av + cf * (((s0+s1)+(s2+s3)) + ((s4+s5)+(s6+s7)));
    float mm = wave_max64(xv2), e2 = expf(xv2 - mm), ss2 = wave_sum64(e2);
    float nxt = e2 / ss2;
    astore(&dst[row * N_C + lane], nxt);
    const int ph = t + 2;
    dm = wave_max64(fabsf(nxt - cur));
    if (lane == 0) atomicMax(&sdm[ph & 1], __float_as_int(dm));
    __syncthreads();
    if (wv == 0) pbar_wave0(bflag, bdelta, ph, sdm, &sdelta, lane);
    __syncthreads();
    delta = sdelta;
    prev = cur; cur = nxt; par ^= 1;
  }

  // argmax of y (prev); first occurrence on ties
  float bv = prev; int bi = lane;
  #pragma unroll
  for (int o = 32; o; o >>= 1){
    float ov = __shfl_xor(bv, o, 64); int oi = __shfl_xor(bi, o, 64);
    if (ov > bv || (ov == bv && oi < bi)){ bv = ov; bi = oi; }
  }
  if (lane == 0) out[row] = bi;
}

extern "C" void kernel_launch(void* const* d_in, const int* in_sizes, int n_in,
                              void* d_out, int out_size, void* d_ws, size_t ws_size,
                              hipStream_t stream)
{
  const float* feat_s = (const float*)d_in[0];
  const int*   y_s    = (const int*)d_in[1];
  const float* feat_q = (const float*)d_in[2];
  int* out = (int*)d_out;

  char* wp = (char*)d_ws;
  auto alloc = [&](size_t bytes) -> char* {
    char* p = wp;
    wp += (bytes + 255) & ~(size_t)255;
    return p;
  };
  float*     Dq  = (float*)alloc((size_t)N_Q * N_Q * 4);     // 64 MB
  _Float16*  Xh  = (_Float16*)alloc((size_t)N_Q * DIM * 2);  // 8 MB
  _Float16*  Xl  = (_Float16*)alloc((size_t)N_Q * DIM * 2);  // 8 MB
  float* Pt     = (float*)alloc((size_t)DIM * N_C * 4);
  float* pn     = (float*)alloc(N_C * 4);
  float* qn     = (float*)alloc(N_Q * 4);
  float* d2min  = (float*)alloc(N_Q * 4);
  float* denom  = (float*)alloc(256);
  int*   nbr    = (int*)alloc((size_t)N_Q * KNN * 4);
  float* dnbr   = (float*)alloc((size_t)N_Q * KNN * 4);
  float* sigma  = (float*)alloc(N_Q * 4);
  float* wh     = (float*)alloc((size_t)N_Q * KNN * 4);
  int*   rowptr = (int*)alloc((N_Q + 1) * 4);
  int*   colA   = (int*)alloc((size_t)2 * N_Q * KNN * 4);
  float* wA     = (float*)alloc((size_t)2 * N_Q * KNN * 4);
  float* buf0   = (float*)alloc((size_t)N_Q * N_C * 4);
  float* buf1   = (float*)alloc((size_t)N_Q * N_C * 4);
  // zero-region: rowsum | indeg | fillc | syncw | garr | bflag | bdelta
  const size_t zbytes = (size_t)N_Q*12 + 256 + 2048 + 32768 + 65536;
  char*  zbase  = alloc(zbytes);
  float* rowsum = (float*)(zbase);
  int*   indeg  = (int*)(zbase + N_Q*4);
  int*   fillc  = (int*)(zbase + N_Q*8);
  int*   syncw  = (int*)(zbase + N_Q*12);
  int*   garr   = (int*)(zbase + N_Q*12 + 256);
  int*   bflag  = (int*)(zbase + N_Q*12 + 256 + 2048);
  int*   bdelta = (int*)(zbase + N_Q*12 + 256 + 2048 + 32768);

  hipMemsetAsync(zbase, 0, zbytes, stream);

  proto_kernel <<<N_C, 256, 0, stream>>>(feat_s, y_s, Pt, pn);
  prep_kernel  <<<N_Q, 256, 0, stream>>>(feat_q, qn, Xh, Xl);
  dist_mfma    <<<dim3(N_Q/128, N_Q/128), 256, 0, stream>>>(Xh, Xl, qn, Dq);
  topk_kernel  <<<N_Q, 256, 0, stream>>>(Dq, nbr, dnbr, sigma);

  int* gcnt = &syncw[0];
  int* gen  = &syncw[32];
  const float* Xq = feat_q;
  void* args[] = {&Xq, &Pt, &pn, &qn, &nbr, &dnbr, &sigma,
                  &d2min, &denom, &wh, &rowsum, &indeg, &rowptr, &fillc,
                  &colA, &wA, &buf0, &buf1, &bflag, &bdelta,
                  &gcnt, &gen, &garr, &out};
  hipLaunchCooperativeKernel((void*)tail_loop, dim3(NBLK), dim3(1024), args, 0, stream);
}